// Round 5
// baseline (942.297 us; speedup 1.0000x reference)
//
#include <hip/hip_runtime.h>
#include <math.h>

#define BNF 0.9999950000374997f

constexpr int N    = 2048;
constexpr int C    = 200;
constexpr int HW   = 65536;
constexpr int MAXDEG = 96;

typedef unsigned short u16;
typedef __attribute__((ext_vector_type(8))) short short8;
typedef __attribute__((ext_vector_type(4))) float f32x4;

union Frag { short8 v; ushort4 h[2]; };

__device__ inline u16 f2bf(float x) {
    unsigned int u = __float_as_uint(x);
    unsigned int r = (u + 0x7fffu + ((u >> 16) & 1u)) >> 16;
    return (u16)r;
}

// async global->LDS, 16B per lane, wave-uniform LDS base
__device__ __forceinline__ void gload16(const void* g, void* l) {
    __builtin_amdgcn_global_load_lds(
        (const __attribute__((address_space(1))) unsigned int*)g,
        (__attribute__((address_space(3))) unsigned int*)l, 16, 0, 0);
}

// swizzled LDS offset (u16 units) for a [rows][64] bf16 tile staged linearly by
// gload16 with inverse-swizzled source columns: chunk c of row r lives at
// r*64 + (c ^ (r&7))*8. kb is the logical u16 column (multiple of 4).
__device__ __forceinline__ int swz(int r, int kb) {
    return r * 64 + ((((kb >> 3) ^ r) & 7) << 3) + (kb & 7);
}

// ---------------------------------------------------------------------------
// Q [65536][2048] f32 -> Qbf [i][n] bf16, QbfT [n][i] bf16, csPart[512][2048]
// block: 128i x 128n tile, grid (512, 16).
// ---------------------------------------------------------------------------
__global__ __launch_bounds__(256) void k_conv(const float* __restrict__ Q,
                                              u16* __restrict__ Qbf,
                                              u16* __restrict__ QbfT,
                                              float* __restrict__ csPart) {
    __shared__ __align__(16) u16 T[128][140];
    __shared__ float csL[8][128];
    const int i0 = blockIdx.x * 128, n0 = blockIdx.y * 128;
    const int t = threadIdx.x;
    const int nq = t & 31;        // n-quad
    const int r0 = t >> 5;        // row within 8-row pass
    float cs0 = 0.f, cs1 = 0.f, cs2 = 0.f, cs3 = 0.f;
#pragma unroll 4
    for (int p = 0; p < 16; ++p) {
        int i = i0 + p * 8 + r0;
        float4 v = *(const float4*)&Q[(size_t)i * 2048 + n0 + nq * 4];
        ushort4 h;
        h.x = f2bf(v.x); h.y = f2bf(v.y); h.z = f2bf(v.z); h.w = f2bf(v.w);
        *(ushort4*)&Qbf[(size_t)i * 2048 + n0 + nq * 4] = h;
        int il = p * 8 + r0;
        T[nq * 4 + 0][il] = h.x; T[nq * 4 + 1][il] = h.y;
        T[nq * 4 + 2][il] = h.z; T[nq * 4 + 3][il] = h.w;
        cs0 += v.x; cs1 += v.y; cs2 += v.z; cs3 += v.w;
    }
    csL[r0][nq * 4 + 0] = cs0; csL[r0][nq * 4 + 1] = cs1;
    csL[r0][nq * 4 + 2] = cs2; csL[r0][nq * 4 + 3] = cs3;
    __syncthreads();
    if (t < 128) {
        float s = 0.f;
#pragma unroll
        for (int r = 0; r < 8; ++r) s += csL[r][t];
        csPart[(size_t)blockIdx.x * 2048 + n0 + t] = s;
    }
#pragma unroll
    for (int p = 0; p < 8; ++p) {
        int n = p * 16 + (t >> 4);
        int io = (t & 15) * 8;
        u16* dst = &QbfT[(size_t)(n0 + n) * 65536 + i0 + io];
        *(ushort4*)&dst[0] = *(const ushort4*)&T[n][io];
        *(ushort4*)&dst[4] = *(const ushort4*)&T[n][io + 4];
    }
}

// xf [65536][200] f32 -> xfT [200][65536] bf16. block 128i, grid 512.
__global__ __launch_bounds__(256) void k_convX(const float* __restrict__ xf,
                                               u16* __restrict__ xfT) {
    __shared__ __align__(16) u16 T2[200][140];
    const int i0 = blockIdx.x * 128;
    const int t = threadIdx.x;
    for (int p = 0; p < 25; ++p) {
        int idx = p * 256 + t;          // 128 rows x 50 quads
        int il = idx / 50, cq = idx % 50;
        float4 v = *(const float4*)&xf[(size_t)(i0 + il) * 200 + cq * 4];
        T2[cq * 4 + 0][il] = f2bf(v.x);
        T2[cq * 4 + 1][il] = f2bf(v.y);
        T2[cq * 4 + 2][il] = f2bf(v.z);
        T2[cq * 4 + 3][il] = f2bf(v.w);
    }
    __syncthreads();
    for (int p = 0; p < 13; ++p) {
        int c = p * 16 + (t >> 4);
        if (c < 200) {
            int io = (t & 15) * 8;
            u16* dst = &xfT[(size_t)c * 65536 + i0 + io];
            *(ushort4*)&dst[0] = *(const ushort4*)&T2[c][io];
            *(ushort4*)&dst[4] = *(const ushort4*)&T2[c][io + 4];
        }
    }
}

// cs[n] = sum_ix csPart[ix][n]
__global__ void k_csum(const float* __restrict__ csPart, float* __restrict__ cs) {
    int n = blockIdx.x * 256 + threadIdx.x;
    float s = 0.f;
    for (int ix = 0; ix < 512; ++ix) s += csPart[(size_t)ix * 2048 + n];
    cs[n] = s;
}

// ---------------------------------------------------------------------------
// S[n,c] += sum_i QbfT[n,i]*xfT[c,i] via bf16 MFMA, pure global_load_lds
// pipeline. grid (32 n-tiles, 32 k-splits), block 256 (4 waves).
// LDS: At [64n][64k] swizzled 8KB, Bt [208c][64k] swizzled 26.6KB (rows
// 200..207 never staged; their MFMA columns are discarded).
// ---------------------------------------------------------------------------
__global__ __launch_bounds__(256) void k_bigS(const u16* __restrict__ QbfT,
                                              const u16* __restrict__ xfT,
                                              float* __restrict__ S) {
    __shared__ __align__(16) u16 Bt[208 * 64];
    __shared__ __align__(16) u16 At[64 * 64];
    const int n0 = blockIdx.x * 64;
    const int k0 = blockIdx.y * 2048;
    const int t  = threadIdx.x;
    const int w  = t >> 6, l = t & 63;
    const int ct0 = (w == 0) ? 0 : (4 + (w - 1) * 3);
    const int nct = (w == 0) ? 4 : 3;
    const int srow = l >> 3;                        // row within 8-row group
    const int scol = (((l & 7) ^ (srow & 7)) << 3); // inverse-swizzled u16 col

    f32x4 acc[4][4];
#pragma unroll
    for (int a = 0; a < 4; ++a)
#pragma unroll
        for (int b = 0; b < 4; ++b) acc[a][b] = (f32x4){0.f, 0.f, 0.f, 0.f};

    for (int ks = 0; ks < 2048; ks += 64) {
        if (ks) __syncthreads();   // prev MFMA done before overwrite
        const size_t kcol = (size_t)(k0 + ks) + scol;
        // stage A: 8 x 1KB
        for (int s = w; s < 8; s += 4)
            gload16(&QbfT[(size_t)(n0 + s * 8 + srow) * 65536 + kcol], &At[s * 512]);
        // stage B: 25 x 1KB (rows 0..199)
        for (int s = w; s < 25; s += 4)
            gload16(&xfT[(size_t)(s * 8 + srow) * 65536 + kcol], &Bt[s * 512]);
        __syncthreads();           // drains vmcnt -> LDS ready

#pragma unroll
        for (int sub = 0; sub < 64; sub += 32) {
            const int kb = sub + ((l >> 4) << 2);
            Frag af[4];
#pragma unroll
            for (int nt = 0; nt < 4; ++nt) {
                const int r = nt * 16 + (l & 15);
                af[nt].h[0] = *(const ushort4*)&At[swz(r, kb)];
                af[nt].h[1] = *(const ushort4*)&At[swz(r, kb + 16)];
            }
#pragma unroll
            for (int c = 0; c < 4; ++c) {
                if (c < nct) {
                    const int rb = (ct0 + c) * 16 + (l & 15);
                    Frag bf;
                    bf.h[0] = *(const ushort4*)&Bt[swz(rb, kb)];
                    bf.h[1] = *(const ushort4*)&Bt[swz(rb, kb + 16)];
#pragma unroll
                    for (int nt = 0; nt < 4; ++nt)
                        acc[nt][c] = __builtin_amdgcn_mfma_f32_16x16x32_bf16(
                            af[nt].v, bf.v, acc[nt][c], 0, 0, 0);
                }
            }
        }
    }
#pragma unroll
    for (int nt = 0; nt < 4; ++nt)
#pragma unroll
        for (int c = 0; c < 4; ++c) {
            if (c < nct) {
                const int cc = (ct0 + c) * 16 + (l & 15);
                if (cc < 200) {
                    const int nbase = n0 + nt * 16 + ((l >> 4) << 2);
#pragma unroll
                    for (int r = 0; r < 4; ++r)
                        atomicAdd(&S[(size_t)(nbase + r) * 200 + cc], acc[nt][c][r]);
                }
            }
        }
}

// xn = BN * S / colsum ; xg = BN * xn
__global__ void k_norm(const float* __restrict__ S, const float* __restrict__ cs,
                       float* __restrict__ xn, float* __restrict__ xg) {
    int i = blockIdx.x * 256 + threadIdx.x;
    if (i >= N * C) return;
    int n = i / C;
    float v = BNF * S[i] / cs[n];
    xn[i] = v;
    xg[i] = BNF * v;
}

// CSR build: one wave per row, order-preserving compaction via ballot.
__global__ void k_csr(const float* __restrict__ adj, int* __restrict__ deg,
                      int* __restrict__ idxs) {
    int w = threadIdx.x >> 6, lane = threadIdx.x & 63;
    int n = blockIdx.x * 4 + w;
    const float* row = adj + (size_t)n * N;
    int base = 0;
    for (int c = 0; c < N; c += 64) {
        float v = row[c + lane];
        bool p = v > 0.f;
        unsigned long long m = __ballot(p);
        int pos = __popcll(m & ((1ull << lane) - 1ull));
        if (p && (base + pos) < MAXDEG) idxs[(size_t)n * MAXDEG + base + pos] = c + lane;
        base += __popcll(m);
    }
    if (lane == 0) deg[n] = base < MAXDEG ? base : MAXDEG;
}

// C[r, coff+c] = scale * sum_k A[r,k] * W[z][k,c]   (generic small dense mm)
__global__ __launch_bounds__(256) void k_mm(const float* __restrict__ A,
                                            const float* __restrict__ W,
                                            float* __restrict__ Cc,
                                            int K, int Wout, int ostride,
                                            int zc_off, int zw_str, float scale) {
    __shared__ float ldsA[32][33];
    __shared__ float ldsW[32][64];
    const int rt = blockIdx.x * 32;
    const int ct = blockIdx.y * 64;
    const int z  = blockIdx.z;
    const float* Wp = W + (size_t)z * zw_str;
    const int coff = z * zc_off;
    const int t = threadIdx.x;
    const int lane = t & 63, wg = t >> 6;
    float acc[8];
#pragma unroll
    for (int r = 0; r < 8; ++r) acc[r] = 0.f;

    for (int k0 = 0; k0 < K; k0 += 32) {
        for (int idx = t; idx < 32 * 32; idx += 256) {
            int r = idx >> 5, kk = idx & 31;
            int k = k0 + kk;
            ldsA[r][kk] = (k < K) ? A[(size_t)(rt + r) * K + k] : 0.f;
        }
        for (int idx = t; idx < 32 * 64; idx += 256) {
            int kk = idx >> 6, c = idx & 63;
            int k = k0 + kk, cg = ct + c;
            ldsW[kk][c] = (k < K && cg < Wout) ? Wp[(size_t)k * Wout + cg] : 0.f;
        }
        __syncthreads();
#pragma unroll 8
        for (int kk = 0; kk < 32; ++kk) {
            float wv = ldsW[kk][lane];
#pragma unroll
            for (int r = 0; r < 8; ++r) acc[r] += ldsA[wg * 8 + r][kk] * wv;
        }
        __syncthreads();
    }
    int cg = ct + lane;
    if (cg < Wout) {
#pragma unroll
        for (int r = 0; r < 8; ++r)
            Cc[(size_t)(rt + wg * 8 + r) * ostride + coff + cg] = scale * acc[r];
    }
}

// out[n,k] = (res?res[n,k]:0) + act( s*(sum_{m in nbr(n)} h[m,k] + bias[k]) )
__global__ void k_spmm(const float* __restrict__ h, const int* __restrict__ deg,
                       const int* __restrict__ idxs, const float* __restrict__ bias,
                       const float* __restrict__ res, float* __restrict__ out,
                       int W, float s, int act) {
    int n = blockIdx.x;
    int d = deg[n];
    const int* row = idxs + (size_t)n * MAXDEG;
    int k0 = threadIdx.x;
    int k1 = threadIdx.x + 128;
    float a0 = 0.f, a1 = 0.f;
    for (int j = 0; j < d; ++j) {
        const float* hr = h + (size_t)row[j] * W;
        a0 += hr[k0];
        if (k1 < W) a1 += hr[k1];
    }
    {
        float v = s * (a0 + bias[k0]);
        if (act) v = v >= 0.f ? v : 0.01f * v;
        if (res) v += res[(size_t)n * W + k0];
        out[(size_t)n * W + k0] = v;
    }
    if (k1 < W) {
        float v = s * (a1 + bias[k1]);
        if (act) v = v >= 0.f ? v : 0.01f * v;
        if (res) v += res[(size_t)n * W + k1];
        out[(size_t)n * W + k1] = v;
    }
}

// f1[h,n] = Wh[n,:128].a[h,:128] ; f2[h,n] = Wh[n,:128].a[h,128:]
__global__ void k_f1f2(const float* __restrict__ WhB, const float* __restrict__ gat_a,
                       float* __restrict__ f1, float* __restrict__ f2) {
    int n = blockIdx.x;
    int h = threadIdx.x >> 6, lane = threadIdx.x & 63;
    const float* row = WhB + (size_t)n * 512 + h * 128;
    const float* a = gat_a + h * 256;
    float v1 = row[lane] * a[lane] + row[lane + 64] * a[lane + 64];
    float v2 = row[lane] * a[128 + lane] + row[lane + 64] * a[128 + lane + 64];
#pragma unroll
    for (int off = 32; off; off >>= 1) { v1 += __shfl_down(v1, off); v2 += __shfl_down(v2, off); }
    if (lane == 0) { f1[h * N + n] = v1; f2[h * N + n] = v2; }
}

// per-head masked-softmax attention + ELU, writes hcat[n, h*128+k]
__global__ void k_att_head(const float* __restrict__ WhB, const float* __restrict__ f1,
                           const float* __restrict__ f2, const int* __restrict__ deg,
                           const int* __restrict__ idxs, float* __restrict__ hcat) {
    int n = blockIdx.x, h = blockIdx.y;
    int k = threadIdx.x;
    int d = deg[n];
    const int* row = idxs + (size_t)n * MAXDEG;
    float f1v = f1[h * N + n];
    const float* f2h = f2 + h * N;
    float mx = -1e30f;
    for (int j = 0; j < d; ++j) {
        float e = f1v + f2h[row[j]];
        e = e >= 0.f ? e : 0.2f * e;
        mx = fmaxf(mx, e);
    }
    float ssum = 0.f, acc = 0.f;
    for (int j = 0; j < d; ++j) {
        int m = row[j];
        float e = f1v + f2h[m];
        e = e >= 0.f ? e : 0.2f * e;
        float w = __expf(e - mx);
        ssum += w;
        acc += w * WhB[(size_t)m * 512 + h * 128 + k];
    }
    float v = acc / ssum;
    v = v > 0.f ? v : __expf(v) - 1.f;   // elu
    hcat[(size_t)n * 512 + h * 128 + k] = v;
}

// f1o/f2o for the output attention (dot with out_a halves), wave per row
__global__ void k_fo(const float* __restrict__ WhO, const float* __restrict__ out_a,
                     float* __restrict__ f1o, float* __restrict__ f2o) {
    int w = threadIdx.x >> 6, lane = threadIdx.x & 63;
    int n = blockIdx.x * 4 + w;
    float x = WhO[(size_t)n * 64 + lane];
    float v1 = x * out_a[lane];
    float v2 = x * out_a[64 + lane];
#pragma unroll
    for (int off = 32; off; off >>= 1) { v1 += __shfl_down(v1, off); v2 += __shfl_down(v2, off); }
    if (lane == 0) { f1o[n] = v1; f2o[n] = v2; }
}

// output attention + elu + bn + lrelu(0.01) -> GAT_x
__global__ void k_att_out(const float* __restrict__ WhO, const float* __restrict__ f1o,
                          const float* __restrict__ f2o, const int* __restrict__ deg,
                          const int* __restrict__ idxs, float* __restrict__ GATx) {
    int n = blockIdx.x;
    int k = threadIdx.x;   // 64
    int d = deg[n];
    const int* row = idxs + (size_t)n * MAXDEG;
    float f1v = f1o[n];
    float mx = -1e30f;
    for (int j = 0; j < d; ++j) {
        float e = f1v + f2o[row[j]];
        e = e >= 0.f ? e : 0.2f * e;
        mx = fmaxf(mx, e);
    }
    float ssum = 0.f, acc = 0.f;
    for (int j = 0; j < d; ++j) {
        int m = row[j];
        float e = f1v + f2o[m];
        e = e >= 0.f ? e : 0.2f * e;
        float w = __expf(e - mx);
        ssum += w;
        acc += w * WhO[(size_t)m * 64 + k];
    }
    float v = acc / ssum;
    v = v > 0.f ? v : __expf(v) - 1.f;   // elu
    v *= BNF;
    GATx[(size_t)n * 64 + k] = v >= 0.f ? v : 0.01f * v;
}

// adaptive fusion + 1x1 conv + bn + lrelu(0.2) -> yT [64][2048] bf16
__global__ void k_fuse(const float* __restrict__ GCNx, const float* __restrict__ GATx,
                       const float* __restrict__ Wf, const float* __restrict__ bfp,
                       const float* __restrict__ cw, const float* __restrict__ cb,
                       u16* __restrict__ yT) {
    int i = blockIdx.x * 256 + threadIdx.x;
    if (i >= N * 64) return;
    int f = i & 63, n = i >> 6;
    float g = GCNx[i], t = GATx[i];
    float mn = fminf(g, t), mxv = fmaxf(g, t);
    float avg = g * Wf[f] + bfp[f] + t * Wf[64 + f] + bfp[64 + f];
    float base = g + t;
    float yv = cw[0] * (mn + base) + cw[1] * (mxv + base) + cw[2] * (avg + base) + cb[0];
    yv *= BNF;
    float v = yv >= 0.f ? yv : 0.2f * yv;
    yT[f * 2048 + n] = f2bf(v);
}

// ---------------------------------------------------------------------------
// out[i,f] += sum_n Qbf[i,n]*yT[f,n], pure gload_lds pipeline, K-split 2.
// grid (1024, 2), tile 64i x 64f, LDS 16KB swizzled, atomic f32 epilogue.
// ---------------------------------------------------------------------------
__global__ __launch_bounds__(256) void k_final(const u16* __restrict__ Qbf,
                                               const u16* __restrict__ yT,
                                               float* __restrict__ out) {
    __shared__ __align__(16) u16 Aq[64 * 64];
    __shared__ __align__(16) u16 By[64 * 64];
    const int i0 = blockIdx.x * 64;
    const int nb = blockIdx.y * 1024;
    const int t = threadIdx.x, w = t >> 6, l = t & 63;
    const int srow = l >> 3;
    const int scol = (((l & 7) ^ (srow & 7)) << 3);
    f32x4 acc[4];
#pragma unroll
    for (int b = 0; b < 4; ++b) acc[b] = (f32x4){0.f, 0.f, 0.f, 0.f};

    for (int ks = 0; ks < 1024; ks += 64) {
        if (ks) __syncthreads();
        const size_t kcol = (size_t)(nb + ks) + scol;
        for (int s = w; s < 8; s += 4) {
            gload16(&Qbf[(size_t)(i0 + s * 8 + srow) * 2048 + kcol], &Aq[s * 512]);
            gload16(&yT[(size_t)(s * 8 + srow) * 2048 + kcol], &By[s * 512]);
        }
        __syncthreads();
#pragma unroll
        for (int sub = 0; sub < 64; sub += 32) {
            const int kb = sub + ((l >> 4) << 2);
            Frag a;
            const int ra = w * 16 + (l & 15);
            a.h[0] = *(const ushort4*)&Aq[swz(ra, kb)];
            a.h[1] = *(const ushort4*)&Aq[swz(ra, kb + 16)];
#pragma unroll
            for (int ft = 0; ft < 4; ++ft) {
                const int rb = ft * 16 + (l & 15);
                Frag b;
                b.h[0] = *(const ushort4*)&By[swz(rb, kb)];
                b.h[1] = *(const ushort4*)&By[swz(rb, kb + 16)];
                acc[ft] = __builtin_amdgcn_mfma_f32_16x16x32_bf16(a.v, b.v, acc[ft], 0, 0, 0);
            }
        }
    }
#pragma unroll
    for (int ft = 0; ft < 4; ++ft) {
        const int i = i0 + w * 16 + ((l >> 4) << 2);
        const int f = ft * 16 + (l & 15);
#pragma unroll
        for (int r = 0; r < 4; ++r)
            atomicAdd(&out[(size_t)(i + r) * 64 + f], acc[ft][r]);
    }
}

extern "C" void kernel_launch(void* const* d_in, const int* in_sizes, int n_in,
                              void* d_out, int out_size, void* d_ws, size_t ws_size,
                              hipStream_t stream) {
    const float* x     = (const float*)d_in[0];
    const float* adj   = (const float*)d_in[1];
    const float* Q     = (const float*)d_in[2];
    const float* g1aW  = (const float*)d_in[3];
    const float* g1ab  = (const float*)d_in[4];
    const float* g1bW  = (const float*)d_in[5];
    const float* g1bb  = (const float*)d_in[6];
    const float* g2aW  = (const float*)d_in[7];
    const float* g2ab  = (const float*)d_in[8];
    const float* g2bW  = (const float*)d_in[9];
    const float* g2bb  = (const float*)d_in[10];
    const float* gatW  = (const float*)d_in[11];
    const float* gata  = (const float*)d_in[12];
    const float* outW  = (const float*)d_in[13];
    const float* outa  = (const float*)d_in[14];
    const float* Wf    = (const float*)d_in[15];
    const float* bfp   = (const float*)d_in[16];
    const float* convw = (const float*)d_in[17];
    const float* convb = (const float*)d_in[18];

    float* ws   = (float*)d_ws;
    float* S    = ws;
    float* cs   = ws + 409600;
    float* xn   = ws + 411648;
    float* xg   = ws + 821248;
    float* xg2  = ws + 1230848;
    float* hbuf = ws + 1640448;
    float* zbuf = ws + 2050048;
    float* WhO  = ws + 2312192;
    float* GCNx = ws + 2443264;
    float* GATx = ws + 2574336;
    float* f1   = ws + 2836480;
    float* f2   = ws + 2844672;
    float* f1o  = ws + 2852864;
    float* f2o  = ws + 2854912;
    int*   deg  = (int*)(ws + 2856960);
    int*   idxs = (int*)(ws + 2859008);
    // yT reuses hbuf region (dead after GCN branch; k_fuse runs after)
    u16*   yT   = (u16*)(ws + 1640448);
    // big bf16 buffers
    float* csPart = ws + 3000000;                 // 512*2048 f32 = 4MB
    u16*   QbfT   = (u16*)(ws + 4200000);         // 2048*65536 u16 = 256MB
    u16*   Qbf    = (u16*)(ws + 71308864);        // 65536*2048 u16 = 256MB
    u16*   xfT    = (u16*)(ws + 138417728);       // 200*65536 u16 = 26MB

    float* out  = (float*)d_out;
    float* WhB  = out;             // 2048*512 scratch inside d_out
    float* hcat = out + 1048576;   // 2048*512 scratch inside d_out

    // zero atomic target S
    hipMemsetAsync(S, 0, 409600 * sizeof(float), stream);

    // ---- bf16 conversion passes ----
    k_conv<<<dim3(512, 16), 256, 0, stream>>>(Q, Qbf, QbfT, csPart);
    k_convX<<<512, 256, 0, stream>>>(x, xfT);
    k_csum<<<8, 256, 0, stream>>>(csPart, cs);

    k_bigS<<<dim3(32, 32), 256, 0, stream>>>(QbfT, xfT, S);
    k_norm<<<(N * C + 255) / 256, 256, 0, stream>>>(S, cs, xn, xg);
    k_csr<<<N / 4, 256, 0, stream>>>(adj, deg, idxs);

    // ---- GCN branch ----
    k_mm<<<dim3(64, 2, 1), 256, 0, stream>>>(xg, g1aW, hbuf, 200, 128, 128, 0, 0, BNF);
    k_spmm<<<N, 128, 0, stream>>>(hbuf, deg, idxs, g1ab, nullptr, zbuf, 128, 1.f, 1);
    k_mm<<<dim3(64, 4, 1), 256, 0, stream>>>(zbuf, g1bW, hbuf, 128, 200, 200, 0, 0, BNF);
    k_spmm<<<N, 128, 0, stream>>>(hbuf, deg, idxs, g1bb, xg, xg2, 200, BNF, 1);
    k_mm<<<dim3(64, 2, 1), 256, 0, stream>>>(xg2, g2aW, hbuf, 200, 128, 128, 0, 0, BNF);
    k_spmm<<<N, 128, 0, stream>>>(hbuf, deg, idxs, g2ab, nullptr, zbuf, 128, 1.f, 1);
    k_mm<<<dim3(64, 1, 1), 256, 0, stream>>>(zbuf, g2bW, hbuf, 128, 64, 64, 0, 0, BNF);
    k_spmm<<<N, 64, 0, stream>>>(hbuf, deg, idxs, g2bb, nullptr, GCNx, 64, BNF, 1);

    // ---- GAT branch ----
    k_mm<<<dim3(64, 2, 4), 256, 0, stream>>>(xn, gatW, WhB, 200, 128, 512, 128, 25600, 1.f);
    k_f1f2<<<N, 256, 0, stream>>>(WhB, gata, f1, f2);
    k_att_head<<<dim3(N, 4), 128, 0, stream>>>(WhB, f1, f2, deg, idxs, hcat);
    k_mm<<<dim3(64, 1, 1), 256, 0, stream>>>(hcat, outW, WhO, 512, 64, 64, 0, 0, 1.f);

    // d_out scratch (WhB/hcat) now dead -> zero it for k_final's atomics
    hipMemsetAsync(d_out, 0, (size_t)out_size * sizeof(float), stream);

    k_fo<<<N / 4, 256, 0, stream>>>(WhO, outa, f1o, f2o);
    k_att_out<<<N, 64, 0, stream>>>(WhO, f1o, f2o, deg, idxs, GATx);

    // ---- fusion (emits bf16 yT) + final projection ----
    k_fuse<<<(N * 64 + 255) / 256, 256, 0, stream>>>(GCNx, GATx, Wf, bfp, convw, convb, yT);
    k_final<<<dim3(HW / 64, 2), 256, 0, stream>>>(Qbf, yT, out);
}

// Round 6
// 930.150 us; speedup vs baseline: 1.0131x; 1.0131x over previous
//
#include <hip/hip_runtime.h>
#include <math.h>

#define BNF 0.9999950000374997f

constexpr int N    = 2048;
constexpr int C    = 200;
constexpr int HW   = 65536;
constexpr int MAXDEG = 96;

typedef unsigned short u16;
typedef __attribute__((ext_vector_type(8))) short short8;
typedef __attribute__((ext_vector_type(4))) float f32x4;

union Frag { short8 v; ushort4 h[2]; };

__device__ inline u16 f2bf(float x) {
    unsigned int u = __float_as_uint(x);
    unsigned int r = (u + 0x7fffu + ((u >> 16) & 1u)) >> 16;
    return (u16)r;
}

// async global->LDS, 16B per lane, wave-uniform LDS base
__device__ __forceinline__ void gload16(const void* g, void* l) {
    __builtin_amdgcn_global_load_lds(
        (const __attribute__((address_space(1))) unsigned int*)g,
        (__attribute__((address_space(3))) unsigned int*)l, 16, 0, 0);
}

// swizzled LDS offset (u16 units) for a [rows][64] bf16 tile staged linearly by
// gload16 with inverse-swizzled source columns: chunk c of row r lives at
// r*64 + (c ^ (r&7))*8. kb is the logical u16 column (multiple of 4).
__device__ __forceinline__ int swz(int r, int kb) {
    return r * 64 + ((((kb >> 3) ^ r) & 7) << 3) + (kb & 7);
}

// ---------------------------------------------------------------------------
// Q [65536][2048] f32 -> Qbf [i][n] bf16, QbfT [n][i] bf16, csPart[512][2048]
// ---------------------------------------------------------------------------
__global__ __launch_bounds__(256) void k_conv(const float* __restrict__ Q,
                                              u16* __restrict__ Qbf,
                                              u16* __restrict__ QbfT,
                                              float* __restrict__ csPart) {
    __shared__ __align__(16) u16 T[128][140];
    __shared__ float csL[8][128];
    const int i0 = blockIdx.x * 128, n0 = blockIdx.y * 128;
    const int t = threadIdx.x;
    const int nq = t & 31;
    const int r0 = t >> 5;
    float cs0 = 0.f, cs1 = 0.f, cs2 = 0.f, cs3 = 0.f;
#pragma unroll 4
    for (int p = 0; p < 16; ++p) {
        int i = i0 + p * 8 + r0;
        float4 v = *(const float4*)&Q[(size_t)i * 2048 + n0 + nq * 4];
        ushort4 h;
        h.x = f2bf(v.x); h.y = f2bf(v.y); h.z = f2bf(v.z); h.w = f2bf(v.w);
        *(ushort4*)&Qbf[(size_t)i * 2048 + n0 + nq * 4] = h;
        int il = p * 8 + r0;
        T[nq * 4 + 0][il] = h.x; T[nq * 4 + 1][il] = h.y;
        T[nq * 4 + 2][il] = h.z; T[nq * 4 + 3][il] = h.w;
        cs0 += v.x; cs1 += v.y; cs2 += v.z; cs3 += v.w;
    }
    csL[r0][nq * 4 + 0] = cs0; csL[r0][nq * 4 + 1] = cs1;
    csL[r0][nq * 4 + 2] = cs2; csL[r0][nq * 4 + 3] = cs3;
    __syncthreads();
    if (t < 128) {
        float s = 0.f;
#pragma unroll
        for (int r = 0; r < 8; ++r) s += csL[r][t];
        csPart[(size_t)blockIdx.x * 2048 + n0 + t] = s;
    }
#pragma unroll
    for (int p = 0; p < 8; ++p) {
        int n = p * 16 + (t >> 4);
        int io = (t & 15) * 8;
        u16* dst = &QbfT[(size_t)(n0 + n) * 65536 + i0 + io];
        *(ushort4*)&dst[0] = *(const ushort4*)&T[n][io];
        *(ushort4*)&dst[4] = *(const ushort4*)&T[n][io + 4];
    }
}

// xf [65536][200] f32 -> xfT [200][65536] bf16
__global__ __launch_bounds__(256) void k_convX(const float* __restrict__ xf,
                                               u16* __restrict__ xfT) {
    __shared__ __align__(16) u16 T2[200][140];
    const int i0 = blockIdx.x * 128;
    const int t = threadIdx.x;
    for (int p = 0; p < 25; ++p) {
        int idx = p * 256 + t;
        int il = idx / 50, cq = idx % 50;
        float4 v = *(const float4*)&xf[(size_t)(i0 + il) * 200 + cq * 4];
        T2[cq * 4 + 0][il] = f2bf(v.x);
        T2[cq * 4 + 1][il] = f2bf(v.y);
        T2[cq * 4 + 2][il] = f2bf(v.z);
        T2[cq * 4 + 3][il] = f2bf(v.w);
    }
    __syncthreads();
    for (int p = 0; p < 13; ++p) {
        int c = p * 16 + (t >> 4);
        if (c < 200) {
            int io = (t & 15) * 8;
            u16* dst = &xfT[(size_t)c * 65536 + i0 + io];
            *(ushort4*)&dst[0] = *(const ushort4*)&T2[c][io];
            *(ushort4*)&dst[4] = *(const ushort4*)&T2[c][io + 4];
        }
    }
}

__global__ void k_csum(const float* __restrict__ csPart, float* __restrict__ cs) {
    int n = blockIdx.x * 256 + threadIdx.x;
    float s = 0.f;
    for (int ix = 0; ix < 512; ++ix) s += csPart[(size_t)ix * 2048 + n];
    cs[n] = s;
}

// ---------------------------------------------------------------------------
// S[n,c] += sum_i QbfT[n,i]*xfT[c,i]. Tile 128n x 208c, grid (16, 32 ksplit),
// block 256 (4 waves). Per K-step: 41 gload_lds vs 104 MFMA (w0).
// ---------------------------------------------------------------------------
__global__ __launch_bounds__(256, 2) void k_bigS(const u16* __restrict__ QbfT,
                                                 const u16* __restrict__ xfT,
                                                 float* __restrict__ S) {
    __shared__ __align__(16) u16 Bt[208 * 64];   // rows 200..207 never staged
    __shared__ __align__(16) u16 At[128 * 64];
    const int n0 = blockIdx.x * 128;
    const int k0 = blockIdx.y * 2048;
    const int t  = threadIdx.x;
    const int w  = t >> 6, l = t & 63;
    const int ct0 = (w == 0) ? 0 : (4 + (w - 1) * 3);
    const int nct = (w == 0) ? 4 : 3;
    const int srow = l >> 3;
    const int scol = (((l & 7) ^ (srow & 7)) << 3);

    f32x4 acc[8][4];
#pragma unroll
    for (int a = 0; a < 8; ++a)
#pragma unroll
        for (int b = 0; b < 4; ++b) acc[a][b] = (f32x4){0.f, 0.f, 0.f, 0.f};

    for (int ks = 0; ks < 2048; ks += 64) {
        if (ks) __syncthreads();
        const size_t kcol = (size_t)(k0 + ks) + scol;
        for (int s = w; s < 16; s += 4)
            gload16(&QbfT[(size_t)(n0 + s * 8 + srow) * 65536 + kcol], &At[s * 512]);
        for (int s = w; s < 25; s += 4)
            gload16(&xfT[(size_t)(s * 8 + srow) * 65536 + kcol], &Bt[s * 512]);
        __syncthreads();

#pragma unroll
        for (int sub = 0; sub < 64; sub += 32) {
            const int kb = sub + ((l >> 4) << 2);
            Frag af[8];
#pragma unroll
            for (int nt = 0; nt < 8; ++nt) {
                const int r = nt * 16 + (l & 15);
                af[nt].h[0] = *(const ushort4*)&At[swz(r, kb)];
                af[nt].h[1] = *(const ushort4*)&At[swz(r, kb + 16)];
            }
#pragma unroll
            for (int c = 0; c < 4; ++c) {
                if (c < nct) {
                    const int rb = (ct0 + c) * 16 + (l & 15);
                    Frag bf;
                    bf.h[0] = *(const ushort4*)&Bt[swz(rb, kb)];
                    bf.h[1] = *(const ushort4*)&Bt[swz(rb, kb + 16)];
#pragma unroll
                    for (int nt = 0; nt < 8; ++nt)
                        acc[nt][c] = __builtin_amdgcn_mfma_f32_16x16x32_bf16(
                            af[nt].v, bf.v, acc[nt][c], 0, 0, 0);
                }
            }
        }
    }
#pragma unroll
    for (int nt = 0; nt < 8; ++nt)
#pragma unroll
        for (int c = 0; c < 4; ++c) {
            if (c < nct) {
                const int cc = (ct0 + c) * 16 + (l & 15);
                if (cc < 200) {
                    const int nbase = n0 + nt * 16 + ((l >> 4) << 2);
#pragma unroll
                    for (int r = 0; r < 4; ++r)
                        atomicAdd(&S[(size_t)(nbase + r) * 200 + cc], acc[nt][c][r]);
                }
            }
        }
}

// xn = BN * S / colsum ; xg = BN * xn
__global__ void k_norm(const float* __restrict__ S, const float* __restrict__ cs,
                       float* __restrict__ xn, float* __restrict__ xg) {
    int i = blockIdx.x * 256 + threadIdx.x;
    if (i >= N * C) return;
    int n = i / C;
    float v = BNF * S[i] / cs[n];
    xn[i] = v;
    xg[i] = BNF * v;
}

// CSR build
__global__ void k_csr(const float* __restrict__ adj, int* __restrict__ deg,
                      int* __restrict__ idxs) {
    int w = threadIdx.x >> 6, lane = threadIdx.x & 63;
    int n = blockIdx.x * 4 + w;
    const float* row = adj + (size_t)n * N;
    int base = 0;
    for (int c = 0; c < N; c += 64) {
        float v = row[c + lane];
        bool p = v > 0.f;
        unsigned long long m = __ballot(p);
        int pos = __popcll(m & ((1ull << lane) - 1ull));
        if (p && (base + pos) < MAXDEG) idxs[(size_t)n * MAXDEG + base + pos] = c + lane;
        base += __popcll(m);
    }
    if (lane == 0) deg[n] = base < MAXDEG ? base : MAXDEG;
}

// generic small dense mm (GCN branch)
__global__ __launch_bounds__(256) void k_mm(const float* __restrict__ A,
                                            const float* __restrict__ W,
                                            float* __restrict__ Cc,
                                            int K, int Wout, int ostride,
                                            int zc_off, int zw_str, float scale) {
    __shared__ float ldsA[32][33];
    __shared__ float ldsW[32][64];
    const int rt = blockIdx.x * 32;
    const int ct = blockIdx.y * 64;
    const int z  = blockIdx.z;
    const float* Wp = W + (size_t)z * zw_str;
    const int coff = z * zc_off;
    const int t = threadIdx.x;
    const int lane = t & 63, wg = t >> 6;
    float acc[8];
#pragma unroll
    for (int r = 0; r < 8; ++r) acc[r] = 0.f;

    for (int k0 = 0; k0 < K; k0 += 32) {
        for (int idx = t; idx < 32 * 32; idx += 256) {
            int r = idx >> 5, kk = idx & 31;
            int k = k0 + kk;
            ldsA[r][kk] = (k < K) ? A[(size_t)(rt + r) * K + k] : 0.f;
        }
        for (int idx = t; idx < 32 * 64; idx += 256) {
            int kk = idx >> 6, c = idx & 63;
            int k = k0 + kk, cg = ct + c;
            ldsW[kk][c] = (k < K && cg < Wout) ? Wp[(size_t)k * Wout + cg] : 0.f;
        }
        __syncthreads();
#pragma unroll 8
        for (int kk = 0; kk < 32; ++kk) {
            float wv = ldsW[kk][lane];
#pragma unroll
            for (int r = 0; r < 8; ++r) acc[r] += ldsA[wg * 8 + r][kk] * wv;
        }
        __syncthreads();
    }
    int cg = ct + lane;
    if (cg < Wout) {
#pragma unroll
        for (int r = 0; r < 8; ++r)
            Cc[(size_t)(rt + wg * 8 + r) * ostride + coff + cg] = scale * acc[r];
    }
}

// out[n,k] = (res?res:0) + act( s*(sum_nbr h + bias) )
__global__ void k_spmm(const float* __restrict__ h, const int* __restrict__ deg,
                       const int* __restrict__ idxs, const float* __restrict__ bias,
                       const float* __restrict__ res, float* __restrict__ out,
                       int W, float s, int act) {
    int n = blockIdx.x;
    int d = deg[n];
    const int* row = idxs + (size_t)n * MAXDEG;
    int k0 = threadIdx.x;
    int k1 = threadIdx.x + 128;
    float a0 = 0.f, a1 = 0.f;
    for (int j = 0; j < d; ++j) {
        const float* hr = h + (size_t)row[j] * W;
        a0 += hr[k0];
        if (k1 < W) a1 += hr[k1];
    }
    {
        float v = s * (a0 + bias[k0]);
        if (act) v = v >= 0.f ? v : 0.01f * v;
        if (res) v += res[(size_t)n * W + k0];
        out[(size_t)n * W + k0] = v;
    }
    if (k1 < W) {
        float v = s * (a1 + bias[k1]);
        if (act) v = v >= 0.f ? v : 0.01f * v;
        if (res) v += res[(size_t)n * W + k1];
        out[(size_t)n * W + k1] = v;
    }
}

// ---------------------------------------------------------------------------
// Wh = xn @ gat_W[h]  (32 rows x 128 cols per block) + f1/f2 row-dot epilogue.
// grid (64, 4 heads), block 256.
// ---------------------------------------------------------------------------
__global__ __launch_bounds__(256) void k_gatWh(const float* __restrict__ xn,
                                               const float* __restrict__ gatW,
                                               const float* __restrict__ gata,
                                               float* __restrict__ WhB,
                                               float* __restrict__ f1,
                                               float* __restrict__ f2) {
    __shared__ float ldsA[32][33];
    __shared__ float ldsW[32][128];
    __shared__ float ldsWh[32][129];
    const int rt = blockIdx.x * 32;
    const int h  = blockIdx.y;
    const float* Wp = gatW + (size_t)h * 200 * 128;
    const int t = threadIdx.x;
    const int col = t & 127, rg = t >> 7;
    float acc[16];
#pragma unroll
    for (int r = 0; r < 16; ++r) acc[r] = 0.f;

    for (int k0 = 0; k0 < 200; k0 += 32) {
        for (int idx = t; idx < 32 * 32; idx += 256) {
            int r = idx >> 5, kk = idx & 31;
            int k = k0 + kk;
            ldsA[r][kk] = (k < 200) ? xn[(size_t)(rt + r) * 200 + k] : 0.f;
        }
        for (int idx = t; idx < 32 * 128; idx += 256) {
            int kk = idx >> 7, c = idx & 127;
            int k = k0 + kk;
            ldsW[kk][c] = (k < 200) ? Wp[(size_t)k * 128 + c] : 0.f;
        }
        __syncthreads();
#pragma unroll 8
        for (int kk = 0; kk < 32; ++kk) {
            float wv = ldsW[kk][col];
#pragma unroll
            for (int r = 0; r < 16; ++r) acc[r] += ldsA[rg * 16 + r][kk] * wv;
        }
        __syncthreads();
    }
#pragma unroll
    for (int r = 0; r < 16; ++r) {
        ldsWh[rg * 16 + r][col] = acc[r];
        WhB[(size_t)(rt + rg * 16 + r) * 512 + h * 128 + col] = acc[r];
    }
    __syncthreads();
    // f1/f2: 8 threads per row
    int row = t >> 3, p = t & 7;
    const float* a = gata + h * 256;
    float s1 = 0.f, s2 = 0.f;
#pragma unroll
    for (int j = 0; j < 16; ++j) {
        int c = p * 16 + j;
        float v = ldsWh[row][c];
        s1 += v * a[c]; s2 += v * a[128 + c];
    }
    s1 += __shfl_xor(s1, 1); s1 += __shfl_xor(s1, 2); s1 += __shfl_xor(s1, 4);
    s2 += __shfl_xor(s2, 1); s2 += __shfl_xor(s2, 2); s2 += __shfl_xor(s2, 4);
    if (p == 0) { f1[h * N + rt + row] = s1; f2[h * N + rt + row] = s2; }
}

// per-head masked-softmax attention + ELU -> hcat[n, h*128+k]
__global__ void k_att_head(const float* __restrict__ WhB, const float* __restrict__ f1,
                           const float* __restrict__ f2, const int* __restrict__ deg,
                           const int* __restrict__ idxs, float* __restrict__ hcat) {
    int n = blockIdx.x, h = blockIdx.y;
    int k = threadIdx.x;
    int d = deg[n];
    const int* row = idxs + (size_t)n * MAXDEG;
    float f1v = f1[h * N + n];
    const float* f2h = f2 + h * N;
    float mx = -1e30f;
    for (int j = 0; j < d; ++j) {
        float e = f1v + f2h[row[j]];
        e = e >= 0.f ? e : 0.2f * e;
        mx = fmaxf(mx, e);
    }
    float ssum = 0.f, acc = 0.f;
    for (int j = 0; j < d; ++j) {
        int m = row[j];
        float e = f1v + f2h[m];
        e = e >= 0.f ? e : 0.2f * e;
        float w = __expf(e - mx);
        ssum += w;
        acc += w * WhB[(size_t)m * 512 + h * 128 + k];
    }
    float v = acc / ssum;
    v = v > 0.f ? v : __expf(v) - 1.f;
    hcat[(size_t)n * 512 + h * 128 + k] = v;
}

// ---------------------------------------------------------------------------
// WhO = hcat @ outW (32x64 per block, K=512) + f1o/f2o row-dot epilogue.
// ---------------------------------------------------------------------------
__global__ __launch_bounds__(256) void k_mmO(const float* __restrict__ hcat,
                                             const float* __restrict__ outW,
                                             const float* __restrict__ outa,
                                             float* __restrict__ WhO,
                                             float* __restrict__ f1o,
                                             float* __restrict__ f2o) {
    __shared__ float ldsA[32][33];
    __shared__ float ldsW[32][64];
    const int rt = blockIdx.x * 32;
    const int t = threadIdx.x;
    const int lane = t & 63, wg = t >> 6;
    float acc[8];
#pragma unroll
    for (int r = 0; r < 8; ++r) acc[r] = 0.f;

    for (int k0 = 0; k0 < 512; k0 += 32) {
        for (int idx = t; idx < 32 * 32; idx += 256) {
            int r = idx >> 5, kk = idx & 31;
            ldsA[r][kk] = hcat[(size_t)(rt + r) * 512 + k0 + kk];
        }
        for (int idx = t; idx < 32 * 64; idx += 256) {
            int kk = idx >> 6, c = idx & 63;
            ldsW[kk][c] = outW[(size_t)(k0 + kk) * 64 + c];
        }
        __syncthreads();
#pragma unroll 8
        for (int kk = 0; kk < 32; ++kk) {
            float wv = ldsW[kk][lane];
#pragma unroll
            for (int r = 0; r < 8; ++r) acc[r] += ldsA[wg * 8 + r][kk] * wv;
        }
        __syncthreads();
    }
#pragma unroll
    for (int r = 0; r < 8; ++r)
        WhO[(size_t)(rt + wg * 8 + r) * 64 + lane] = acc[r];
#pragma unroll
    for (int r = 0; r < 8; ++r) {
        float v1 = acc[r] * outa[lane];
        float v2 = acc[r] * outa[64 + lane];
#pragma unroll
        for (int off = 32; off; off >>= 1) {
            v1 += __shfl_down(v1, off);
            v2 += __shfl_down(v2, off);
        }
        if (lane == 0) { f1o[rt + wg * 8 + r] = v1; f2o[rt + wg * 8 + r] = v2; }
    }
}

// output attention + elu + bn + lrelu + adaptive fusion + conv + bn + lrelu
// -> yT [64][2048] bf16  (k_fuse folded in; GATx buffer eliminated)
__global__ void k_att_out(const float* __restrict__ WhO, const float* __restrict__ f1o,
                          const float* __restrict__ f2o, const int* __restrict__ deg,
                          const int* __restrict__ idxs, const float* __restrict__ GCNx,
                          const float* __restrict__ Wf, const float* __restrict__ bfp,
                          const float* __restrict__ cw, const float* __restrict__ cb,
                          u16* __restrict__ yT) {
    int n = blockIdx.x;
    int k = threadIdx.x;   // 64
    int d = deg[n];
    const int* row = idxs + (size_t)n * MAXDEG;
    float f1v = f1o[n];
    float mx = -1e30f;
    for (int j = 0; j < d; ++j) {
        float e = f1v + f2o[row[j]];
        e = e >= 0.f ? e : 0.2f * e;
        mx = fmaxf(mx, e);
    }
    float ssum = 0.f, acc = 0.f;
    for (int j = 0; j < d; ++j) {
        int m = row[j];
        float e = f1v + f2o[m];
        e = e >= 0.f ? e : 0.2f * e;
        float w = __expf(e - mx);
        ssum += w;
        acc += w * WhO[(size_t)m * 64 + k];
    }
    float v = acc / ssum;
    v = v > 0.f ? v : __expf(v) - 1.f;   // elu
    v *= BNF;
    float gat = v >= 0.f ? v : 0.01f * v;
    float g = GCNx[(size_t)n * 64 + k];
    float mn = fminf(g, gat), mxv = fmaxf(g, gat);
    float avg = g * Wf[k] + bfp[k] + gat * Wf[64 + k] + bfp[64 + k];
    float base = g + gat;
    float yv = cw[0] * (mn + base) + cw[1] * (mxv + base) + cw[2] * (avg + base) + cb[0];
    yv *= BNF;
    yv = yv >= 0.f ? yv : 0.2f * yv;
    yT[k * 2048 + n] = f2bf(yv);
}

// ---------------------------------------------------------------------------
// out[i,f] = sum_n Qbf[i,n]*yT[f,n]. Tile 128i x 64f, grid 512, no K-split,
// direct stores (no atomics, no d_out memset).
// ---------------------------------------------------------------------------
__global__ __launch_bounds__(256) void k_final(const u16* __restrict__ Qbf,
                                               const u16* __restrict__ yT,
                                               float* __restrict__ out) {
    __shared__ __align__(16) u16 Aq[128 * 64];
    __shared__ __align__(16) u16 By[64 * 64];
    const int i0 = blockIdx.x * 128;
    const int t = threadIdx.x, w = t >> 6, l = t & 63;
    const int srow = l >> 3;
    const int scol = (((l & 7) ^ (srow & 7)) << 3);
    f32x4 acc[2][4];
#pragma unroll
    for (int a = 0; a < 2; ++a)
#pragma unroll
        for (int b = 0; b < 4; ++b) acc[a][b] = (f32x4){0.f, 0.f, 0.f, 0.f};

    for (int n0 = 0; n0 < 2048; n0 += 64) {
        if (n0) __syncthreads();
        const size_t kcol = (size_t)n0 + scol;
        for (int s = w; s < 16; s += 4)
            gload16(&Qbf[(size_t)(i0 + s * 8 + srow) * 2048 + kcol], &Aq[s * 512]);
        for (int s = w; s < 8; s += 4)
            gload16(&yT[(size_t)(s * 8 + srow) * 2048 + kcol], &By[s * 512]);
        __syncthreads();
#pragma unroll
        for (int sub = 0; sub < 64; sub += 32) {
            const int kb = sub + ((l >> 4) << 2);
            Frag a[2];
#pragma unroll
            for (int it = 0; it < 2; ++it) {
                const int ra = w * 32 + it * 16 + (l & 15);
                a[it].h[0] = *(const ushort4*)&Aq[swz(ra, kb)];
                a[it].h[1] = *(const ushort4*)&Aq[swz(ra, kb + 16)];
            }
#pragma unroll
            for (int ft = 0; ft < 4; ++ft) {
                const int rb = ft * 16 + (l & 15);
                Frag b;
                b.h[0] = *(const ushort4*)&By[swz(rb, kb)];
                b.h[1] = *(const ushort4*)&By[swz(rb, kb + 16)];
#pragma unroll
                for (int it = 0; it < 2; ++it)
                    acc[it][ft] = __builtin_amdgcn_mfma_f32_16x16x32_bf16(
                        a[it].v, b.v, acc[it][ft], 0, 0, 0);
            }
        }
    }
#pragma unroll
    for (int it = 0; it < 2; ++it)
#pragma unroll
        for (int ft = 0; ft < 4; ++ft) {
            const int i = i0 + w * 32 + it * 16 + ((l >> 4) << 2);
            const int f = ft * 16 + (l & 15);
#pragma unroll
            for (int r = 0; r < 4; ++r)
                out[(size_t)(i + r) * 64 + f] = acc[it][ft][r];
        }
}

extern "C" void kernel_launch(void* const* d_in, const int* in_sizes, int n_in,
                              void* d_out, int out_size, void* d_ws, size_t ws_size,
                              hipStream_t stream) {
    const float* x     = (const float*)d_in[0];
    const float* adj   = (const float*)d_in[1];
    const float* Q     = (const float*)d_in[2];
    const float* g1aW  = (const float*)d_in[3];
    const float* g1ab  = (const float*)d_in[4];
    const float* g1bW  = (const float*)d_in[5];
    const float* g1bb  = (const float*)d_in[6];
    const float* g2aW  = (const float*)d_in[7];
    const float* g2ab  = (const float*)d_in[8];
    const float* g2bW  = (const float*)d_in[9];
    const float* g2bb  = (const float*)d_in[10];
    const float* gatW  = (const float*)d_in[11];
    const float* gata  = (const float*)d_in[12];
    const float* outW  = (const float*)d_in[13];
    const float* outa  = (const float*)d_in[14];
    const float* Wf    = (const float*)d_in[15];
    const float* bfp   = (const float*)d_in[16];
    const float* convw = (const float*)d_in[17];
    const float* convb = (const float*)d_in[18];

    float* ws   = (float*)d_ws;
    float* S    = ws;
    float* cs   = ws + 409600;
    float* xn   = ws + 411648;
    float* xg   = ws + 821248;
    float* xg2  = ws + 1230848;
    float* hbuf = ws + 1640448;
    float* zbuf = ws + 2050048;
    float* WhO  = ws + 2312192;
    float* GCNx = ws + 2443264;
    float* f1   = ws + 2836480;
    float* f2   = ws + 2844672;
    float* f1o  = ws + 2852864;
    float* f2o  = ws + 2854912;
    int*   deg  = (int*)(ws + 2856960);
    int*   idxs = (int*)(ws + 2859008);
    // yT reuses hbuf region (hbuf dead after last GCN spmm; k_att_out writes yT)
    u16*   yT   = (u16*)(ws + 1640448);
    // big bf16 buffers
    float* csPart = ws + 3000000;                 // 512*2048 f32
    u16*   QbfT   = (u16*)(ws + 4200000);         // 2048*65536 u16 = 256MB
    u16*   Qbf    = (u16*)(ws + 71308864);        // 65536*2048 u16 = 256MB
    u16*   xfT    = (u16*)(ws + 138417728);       // 200*65536 u16 = 26MB

    float* out  = (float*)d_out;
    float* WhB  = out;             // 2048*512 scratch inside d_out
    float* hcat = out + 1048576;   // 2048*512 scratch inside d_out

    // zero atomic target S
    hipMemsetAsync(S, 0, 409600 * sizeof(float), stream);

    // ---- bf16 conversion passes ----
    k_conv<<<dim3(512, 16), 256, 0, stream>>>(Q, Qbf, QbfT, csPart);
    k_convX<<<512, 256, 0, stream>>>(x, xfT);
    k_csum<<<8, 256, 0, stream>>>(csPart, cs);

    k_bigS<<<dim3(16, 32), 256, 0, stream>>>(QbfT, xfT, S);
    k_norm<<<(N * C + 255) / 256, 256, 0, stream>>>(S, cs, xn, xg);
    k_csr<<<N / 4, 256, 0, stream>>>(adj, deg, idxs);

    // ---- GCN branch ----
    k_mm<<<dim3(64, 2, 1), 256, 0, stream>>>(xg, g1aW, hbuf, 200, 128, 128, 0, 0, BNF);
    k_spmm<<<N, 128, 0, stream>>>(hbuf, deg, idxs, g1ab, nullptr, zbuf, 128, 1.f, 1);
    k_mm<<<dim3(64, 4, 1), 256, 0, stream>>>(zbuf, g1bW, hbuf, 128, 200, 200, 0, 0, BNF);
    k_spmm<<<N, 128, 0, stream>>>(hbuf, deg, idxs, g1bb, xg, xg2, 200, BNF, 1);
    k_mm<<<dim3(64, 2, 1), 256, 0, stream>>>(xg2, g2aW, hbuf, 200, 128, 128, 0, 0, BNF);
    k_spmm<<<N, 128, 0, stream>>>(hbuf, deg, idxs, g2ab, nullptr, zbuf, 128, 1.f, 1);
    k_mm<<<dim3(64, 1, 1), 256, 0, stream>>>(zbuf, g2bW, hbuf, 128, 64, 64, 0, 0, BNF);
    k_spmm<<<N, 64, 0, stream>>>(hbuf, deg, idxs, g2bb, nullptr, GCNx, 64, BNF, 1);

    // ---- GAT branch (f1f2 fused into gatWh, fo fused into mmO) ----
    k_gatWh<<<dim3(64, 4), 256, 0, stream>>>(xn, gatW, gata, WhB, f1, f2);
    k_att_head<<<dim3(N, 4), 128, 0, stream>>>(WhB, f1, f2, deg, idxs, hcat);
    k_mmO<<<64, 256, 0, stream>>>(hcat, outW, outa, WhO, f1o, f2o);

    // ---- output attention + fusion -> yT (writes over hbuf region) ----
    k_att_out<<<N, 64, 0, stream>>>(WhO, f1o, f2o, deg, idxs, GCNx,
                                    Wf, bfp, convw, convb, yT);

    // ---- final projection (direct stores, overwrites WhB/hcat scratch) ----
    k_final<<<512, 256, 0, stream>>>(Qbf, yT, out);
}

// Round 7
// 923.855 us; speedup vs baseline: 1.0200x; 1.0068x over previous
//
#include <hip/hip_runtime.h>
#include <math.h>

#define BNF 0.9999950000374997f

constexpr int N    = 2048;
constexpr int C    = 200;
constexpr int HW   = 65536;
constexpr int MAXDEG = 96;

typedef unsigned short u16;
typedef __attribute__((ext_vector_type(8))) short short8;
typedef __attribute__((ext_vector_type(4))) float f32x4;

union Frag { short8 v; ushort4 h[2]; };

__device__ inline u16 f2bf(float x) {
    unsigned int u = __float_as_uint(x);
    unsigned int r = (u + 0x7fffu + ((u >> 16) & 1u)) >> 16;
    return (u16)r;
}

// async global->LDS, 16B per lane, wave-uniform LDS base, per-lane global addr
__device__ __forceinline__ void gload16(const void* g, void* l) {
    __builtin_amdgcn_global_load_lds(
        (const __attribute__((address_space(1))) unsigned int*)g,
        (__attribute__((address_space(3))) unsigned int*)l, 16, 0, 0);
}

// ---------------------------------------------------------------------------
// Q [65536][2048] f32 -> Qbf [i][n] bf16, QbfT [n][i] bf16, csPart[512][2048]
// ---------------------------------------------------------------------------
__global__ __launch_bounds__(256) void k_conv(const float* __restrict__ Q,
                                              u16* __restrict__ Qbf,
                                              u16* __restrict__ QbfT,
                                              float* __restrict__ csPart) {
    __shared__ __align__(16) u16 T[128][140];
    __shared__ float csL[8][128];
    const int i0 = blockIdx.x * 128, n0 = blockIdx.y * 128;
    const int t = threadIdx.x;
    const int nq = t & 31;
    const int r0 = t >> 5;
    float cs0 = 0.f, cs1 = 0.f, cs2 = 0.f, cs3 = 0.f;
#pragma unroll 4
    for (int p = 0; p < 16; ++p) {
        int i = i0 + p * 8 + r0;
        float4 v = *(const float4*)&Q[(size_t)i * 2048 + n0 + nq * 4];
        ushort4 h;
        h.x = f2bf(v.x); h.y = f2bf(v.y); h.z = f2bf(v.z); h.w = f2bf(v.w);
        *(ushort4*)&Qbf[(size_t)i * 2048 + n0 + nq * 4] = h;
        int il = p * 8 + r0;
        T[nq * 4 + 0][il] = h.x; T[nq * 4 + 1][il] = h.y;
        T[nq * 4 + 2][il] = h.z; T[nq * 4 + 3][il] = h.w;
        cs0 += v.x; cs1 += v.y; cs2 += v.z; cs3 += v.w;
    }
    csL[r0][nq * 4 + 0] = cs0; csL[r0][nq * 4 + 1] = cs1;
    csL[r0][nq * 4 + 2] = cs2; csL[r0][nq * 4 + 3] = cs3;
    __syncthreads();
    if (t < 128) {
        float s = 0.f;
#pragma unroll
        for (int r = 0; r < 8; ++r) s += csL[r][t];
        csPart[(size_t)blockIdx.x * 2048 + n0 + t] = s;
    }
#pragma unroll
    for (int p = 0; p < 8; ++p) {
        int n = p * 16 + (t >> 4);
        int io = (t & 15) * 8;
        u16* dst = &QbfT[(size_t)(n0 + n) * 65536 + i0 + io];
        *(ushort4*)&dst[0] = *(const ushort4*)&T[n][io];
        *(ushort4*)&dst[4] = *(const ushort4*)&T[n][io + 4];
    }
}

// xf [65536][200] f32 -> xfT [208][65536] bf16 (rows 200..207 zeroed)
__global__ __launch_bounds__(256) void k_convX(const float* __restrict__ xf,
                                               u16* __restrict__ xfT) {
    __shared__ __align__(16) u16 T2[208][140];
    const int i0 = blockIdx.x * 128;
    const int t = threadIdx.x;
    for (int p = 0; p < 25; ++p) {
        int idx = p * 256 + t;
        int il = idx / 50, cq = idx % 50;
        float4 v = *(const float4*)&xf[(size_t)(i0 + il) * 200 + cq * 4];
        T2[cq * 4 + 0][il] = f2bf(v.x);
        T2[cq * 4 + 1][il] = f2bf(v.y);
        T2[cq * 4 + 2][il] = f2bf(v.z);
        T2[cq * 4 + 3][il] = f2bf(v.w);
    }
    if (t < 128) {
#pragma unroll
        for (int r = 0; r < 8; ++r) T2[200 + r][t] = 0;
    }
    __syncthreads();
    for (int p = 0; p < 13; ++p) {
        int c = p * 16 + (t >> 4);
        int io = (t & 15) * 8;
        u16* dst = &xfT[(size_t)c * 65536 + i0 + io];
        *(ushort4*)&dst[0] = *(const ushort4*)&T2[c][io];
        *(ushort4*)&dst[4] = *(const ushort4*)&T2[c][io + 4];
    }
}

__global__ void k_csum(const float* __restrict__ csPart, float* __restrict__ cs) {
    int n = blockIdx.x * 256 + threadIdx.x;
    float s = 0.f;
    for (int ix = 0; ix < 512; ++ix) s += csPart[(size_t)ix * 2048 + n];
    cs[n] = s;
}

// ---------------------------------------------------------------------------
// S[n,c] += sum_i QbfT[n,i]*xfT[c,i]. Tile 128n x 208c, K-step 32, dbuf LDS,
// counted vmcnt (T3/T4), XCD-aware remap (16 n-blocks of one k-slab share L2).
// grid 512 flat (16 nt x 32 ks), block 256 (4 waves).
// ---------------------------------------------------------------------------
__global__ __launch_bounds__(256, 2) void k_bigS(const u16* __restrict__ QbfT,
                                                 const u16* __restrict__ xfT,
                                                 float* __restrict__ S) {
    __shared__ __align__(16) u16 At[2][128 * 32];   // 8 KB per buf
    __shared__ __align__(16) u16 Bt[2][208 * 32];   // 13.3 KB per buf
    const int bid = blockIdx.x;
    const int xcd = bid & 7, jj = bid >> 3;
    const int nt_b = jj & 15;
    const int ks_b = ((jj >> 4) << 3) + xcd;        // same-slab blocks -> same XCD
    const int n0 = nt_b * 128;
    const size_t k0 = (size_t)ks_b * 2048;
    const int t = threadIdx.x, w = t >> 6, l = t & 63;
    const int ct0 = (w == 0) ? 0 : (4 + (w - 1) * 3);
    const int nct = (w == 0) ? 4 : 3;
    // staging: seg = 16 rows x 32 u16 (1KB). lane l -> row l>>2, slot l&3.
    // source chunk = slot ^ ((row>>1)&3)  (inverse of read swizzle)
    const int lrow = l >> 2;
    const int scol = (((l & 3) ^ ((l >> 3) & 3)) << 3);

    f32x4 acc[8][4];
#pragma unroll
    for (int a = 0; a < 8; ++a)
#pragma unroll
        for (int b = 0; b < 4; ++b) acc[a][b] = (f32x4){0.f, 0.f, 0.f, 0.f};

#define STAGE_S(buf, step)                                                          \
    {                                                                               \
        const size_t kc = k0 + (size_t)(step) * 32 + scol;                          \
        for (int s = w; s < 8; s += 4)                                              \
            gload16(&QbfT[(size_t)(n0 + s * 16 + lrow) * 65536 + kc],               \
                    &At[buf][s * 512]);                                             \
        for (int s = w; s < 13; s += 4)                                             \
            gload16(&xfT[(size_t)(s * 16 + lrow) * 65536 + kc],                     \
                    &Bt[buf][s * 512]);                                             \
    }

    STAGE_S(0, 0);
    for (int step = 0; step < 64; ++step) {
        const int cur = step & 1;
        if (step + 1 < 64) {
            STAGE_S(cur ^ 1, step + 1);
            if (w == 0) asm volatile("s_waitcnt vmcnt(6)" ::: "memory");
            else        asm volatile("s_waitcnt vmcnt(5)" ::: "memory");
        } else {
            asm volatile("s_waitcnt vmcnt(0)" ::: "memory");
        }
        __builtin_amdgcn_s_barrier();

        const u16* Ab = At[cur];
        const u16* Bb = Bt[cur];
        const int c4 = l >> 4;                       // logical 8-u16 chunk 0..3
        Frag af[8];
#pragma unroll
        for (int nt = 0; nt < 8; ++nt) {
            const int r = nt * 16 + (l & 15);
            af[nt].v = *(const short8*)&Ab[r * 32 + ((c4 ^ ((r >> 1) & 3)) << 3)];
        }
#pragma unroll
        for (int c = 0; c < 4; ++c) {
            if (c < nct) {
                const int rb = (ct0 + c) * 16 + (l & 15);
                Frag bf;
                bf.v = *(const short8*)&Bb[rb * 32 + ((c4 ^ ((rb >> 1) & 3)) << 3)];
#pragma unroll
                for (int nt = 0; nt < 8; ++nt)
                    acc[nt][c] = __builtin_amdgcn_mfma_f32_16x16x32_bf16(
                        af[nt].v, bf.v, acc[nt][c], 0, 0, 0);
            }
        }
        asm volatile("s_waitcnt lgkmcnt(0)" ::: "memory");
        __builtin_amdgcn_s_barrier();
    }
#undef STAGE_S
#pragma unroll
    for (int nt = 0; nt < 8; ++nt)
#pragma unroll
        for (int c = 0; c < 4; ++c) {
            if (c < nct) {
                const int cc = (ct0 + c) * 16 + (l & 15);
                if (cc < 200) {
                    const int nbase = n0 + nt * 16 + ((l >> 4) << 2);
#pragma unroll
                    for (int r = 0; r < 4; ++r)
                        atomicAdd(&S[(size_t)(nbase + r) * 200 + cc], acc[nt][c][r]);
                }
            }
        }
}

// xn = BN * S / colsum ; xg = BN * xn
__global__ void k_norm(const float* __restrict__ S, const float* __restrict__ cs,
                       float* __restrict__ xn, float* __restrict__ xg) {
    int i = blockIdx.x * 256 + threadIdx.x;
    if (i >= N * C) return;
    int n = i / C;
    float v = BNF * S[i] / cs[n];
    xn[i] = v;
    xg[i] = BNF * v;
}

// CSR build
__global__ void k_csr(const float* __restrict__ adj, int* __restrict__ deg,
                      int* __restrict__ idxs) {
    int w = threadIdx.x >> 6, lane = threadIdx.x & 63;
    int n = blockIdx.x * 4 + w;
    const float* row = adj + (size_t)n * N;
    int base = 0;
    for (int c = 0; c < N; c += 64) {
        float v = row[c + lane];
        bool p = v > 0.f;
        unsigned long long m = __ballot(p);
        int pos = __popcll(m & ((1ull << lane) - 1ull));
        if (p && (base + pos) < MAXDEG) idxs[(size_t)n * MAXDEG + base + pos] = c + lane;
        base += __popcll(m);
    }
    if (lane == 0) deg[n] = base < MAXDEG ? base : MAXDEG;
}

// generic small dense mm (GCN branch)
__global__ __launch_bounds__(256) void k_mm(const float* __restrict__ A,
                                            const float* __restrict__ W,
                                            float* __restrict__ Cc,
                                            int K, int Wout, int ostride,
                                            int zc_off, int zw_str, float scale) {
    __shared__ float ldsA[32][33];
    __shared__ float ldsW[32][64];
    const int rt = blockIdx.x * 32;
    const int ct = blockIdx.y * 64;
    const int z  = blockIdx.z;
    const float* Wp = W + (size_t)z * zw_str;
    const int coff = z * zc_off;
    const int t = threadIdx.x;
    const int lane = t & 63, wg = t >> 6;
    float acc[8];
#pragma unroll
    for (int r = 0; r < 8; ++r) acc[r] = 0.f;

    for (int k0 = 0; k0 < K; k0 += 32) {
        for (int idx = t; idx < 32 * 32; idx += 256) {
            int r = idx >> 5, kk = idx & 31;
            int k = k0 + kk;
            ldsA[r][kk] = (k < K) ? A[(size_t)(rt + r) * K + k] : 0.f;
        }
        for (int idx = t; idx < 32 * 64; idx += 256) {
            int kk = idx >> 6, c = idx & 63;
            int k = k0 + kk, cg = ct + c;
            ldsW[kk][c] = (k < K && cg < Wout) ? Wp[(size_t)k * Wout + cg] : 0.f;
        }
        __syncthreads();
#pragma unroll 8
        for (int kk = 0; kk < 32; ++kk) {
            float wv = ldsW[kk][lane];
#pragma unroll
            for (int r = 0; r < 8; ++r) acc[r] += ldsA[wg * 8 + r][kk] * wv;
        }
        __syncthreads();
    }
    int cg = ct + lane;
    if (cg < Wout) {
#pragma unroll
        for (int r = 0; r < 8; ++r)
            Cc[(size_t)(rt + wg * 8 + r) * ostride + coff + cg] = scale * acc[r];
    }
}

// out[n,k] = (res?res:0) + act( s*(sum_nbr h + bias) )
__global__ void k_spmm(const float* __restrict__ h, const int* __restrict__ deg,
                       const int* __restrict__ idxs, const float* __restrict__ bias,
                       const float* __restrict__ res, float* __restrict__ out,
                       int W, float s, int act) {
    int n = blockIdx.x;
    int d = deg[n];
    const int* row = idxs + (size_t)n * MAXDEG;
    int k0 = threadIdx.x;
    int k1 = threadIdx.x + 128;
    float a0 = 0.f, a1 = 0.f;
    for (int j = 0; j < d; ++j) {
        const float* hr = h + (size_t)row[j] * W;
        a0 += hr[k0];
        if (k1 < W) a1 += hr[k1];
    }
    {
        float v = s * (a0 + bias[k0]);
        if (act) v = v >= 0.f ? v : 0.01f * v;
        if (res) v += res[(size_t)n * W + k0];
        out[(size_t)n * W + k0] = v;
    }
    if (k1 < W) {
        float v = s * (a1 + bias[k1]);
        if (act) v = v >= 0.f ? v : 0.01f * v;
        if (res) v += res[(size_t)n * W + k1];
        out[(size_t)n * W + k1] = v;
    }
}

// Wh = xn @ gat_W[h] (32x128 per block) + f1/f2 row-dot epilogue
__global__ __launch_bounds__(256) void k_gatWh(const float* __restrict__ xn,
                                               const float* __restrict__ gatW,
                                               const float* __restrict__ gata,
                                               float* __restrict__ WhB,
                                               float* __restrict__ f1,
                                               float* __restrict__ f2) {
    __shared__ float ldsA[32][33];
    __shared__ float ldsW[32][128];
    __shared__ float ldsWh[32][129];
    const int rt = blockIdx.x * 32;
    const int h  = blockIdx.y;
    const float* Wp = gatW + (size_t)h * 200 * 128;
    const int t = threadIdx.x;
    const int col = t & 127, rg = t >> 7;
    float acc[16];
#pragma unroll
    for (int r = 0; r < 16; ++r) acc[r] = 0.f;

    for (int k0 = 0; k0 < 200; k0 += 32) {
        for (int idx = t; idx < 32 * 32; idx += 256) {
            int r = idx >> 5, kk = idx & 31;
            int k = k0 + kk;
            ldsA[r][kk] = (k < 200) ? xn[(size_t)(rt + r) * 200 + k] : 0.f;
        }
        for (int idx = t; idx < 32 * 128; idx += 256) {
            int kk = idx >> 7, c = idx & 127;
            int k = k0 + kk;
            ldsW[kk][c] = (k < 200) ? Wp[(size_t)k * 128 + c] : 0.f;
        }
        __syncthreads();
#pragma unroll 8
        for (int kk = 0; kk < 32; ++kk) {
            float wv = ldsW[kk][col];
#pragma unroll
            for (int r = 0; r < 16; ++r) acc[r] += ldsA[rg * 16 + r][kk] * wv;
        }
        __syncthreads();
    }
#pragma unroll
    for (int r = 0; r < 16; ++r) {
        ldsWh[rg * 16 + r][col] = acc[r];
        WhB[(size_t)(rt + rg * 16 + r) * 512 + h * 128 + col] = acc[r];
    }
    __syncthreads();
    int row = t >> 3, p = t & 7;
    const float* a = gata + h * 256;
    float s1 = 0.f, s2 = 0.f;
#pragma unroll
    for (int j = 0; j < 16; ++j) {
        int c = p * 16 + j;
        float v = ldsWh[row][c];
        s1 += v * a[c]; s2 += v * a[128 + c];
    }
    s1 += __shfl_xor(s1, 1); s1 += __shfl_xor(s1, 2); s1 += __shfl_xor(s1, 4);
    s2 += __shfl_xor(s2, 1); s2 += __shfl_xor(s2, 2); s2 += __shfl_xor(s2, 4);
    if (p == 0) { f1[h * N + rt + row] = s1; f2[h * N + rt + row] = s2; }
}

// per-head masked-softmax attention + ELU -> hcat[n, h*128+k]
__global__ void k_att_head(const float* __restrict__ WhB, const float* __restrict__ f1,
                           const float* __restrict__ f2, const int* __restrict__ deg,
                           const int* __restrict__ idxs, float* __restrict__ hcat) {
    int n = blockIdx.x, h = blockIdx.y;
    int k = threadIdx.x;
    int d = deg[n];
    const int* row = idxs + (size_t)n * MAXDEG;
    float f1v = f1[h * N + n];
    const float* f2h = f2 + h * N;
    float mx = -1e30f;
    for (int j = 0; j < d; ++j) {
        float e = f1v + f2h[row[j]];
        e = e >= 0.f ? e : 0.2f * e;
        mx = fmaxf(mx, e);
    }
    float ssum = 0.f, acc = 0.f;
    for (int j = 0; j < d; ++j) {
        int m = row[j];
        float e = f1v + f2h[m];
        e = e >= 0.f ? e : 0.2f * e;
        float w = __expf(e - mx);
        ssum += w;
        acc += w * WhB[(size_t)m * 512 + h * 128 + k];
    }
    float v = acc / ssum;
    v = v > 0.f ? v : __expf(v) - 1.f;
    hcat[(size_t)n * 512 + h * 128 + k] = v;
}

// WhO = hcat @ outW (32x64, K=512) + f1o/f2o row-dot epilogue
__global__ __launch_bounds__(256) void k_mmO(const float* __restrict__ hcat,
                                             const float* __restrict__ outW,
                                             const float* __restrict__ outa,
                                             float* __restrict__ WhO,
                                             float* __restrict__ f1o,
                                             float* __restrict__ f2o) {
    __shared__ float ldsA[32][33];
    __shared__ float ldsW[32][64];
    const int rt = blockIdx.x * 32;
    const int t = threadIdx.x;
    const int lane = t & 63, wg = t >> 6;
    float acc[8];
#pragma unroll
    for (int r = 0; r < 8; ++r) acc[r] = 0.f;

    for (int k0 = 0; k0 < 512; k0 += 32) {
        for (int idx = t; idx < 32 * 32; idx += 256) {
            int r = idx >> 5, kk = idx & 31;
            ldsA[r][kk] = hcat[(size_t)(rt + r) * 512 + k0 + kk];
        }
        for (int idx = t; idx < 32 * 64; idx += 256) {
            int kk = idx >> 6, c = idx & 63;
            ldsW[kk][c] = outW[(size_t)(k0 + kk) * 64 + c];
        }
        __syncthreads();
#pragma unroll 8
        for (int kk = 0; kk < 32; ++kk) {
            float wv = ldsW[kk][lane];
#pragma unroll
            for (int r = 0; r < 8; ++r) acc[r] += ldsA[wg * 8 + r][kk] * wv;
        }
        __syncthreads();
    }
#pragma unroll
    for (int r = 0; r < 8; ++r)
        WhO[(size_t)(rt + wg * 8 + r) * 64 + lane] = acc[r];
#pragma unroll
    for (int r = 0; r < 8; ++r) {
        float v1 = acc[r] * outa[lane];
        float v2 = acc[r] * outa[64 + lane];
#pragma unroll
        for (int off = 32; off; off >>= 1) {
            v1 += __shfl_down(v1, off);
            v2 += __shfl_down(v2, off);
        }
        if (lane == 0) { f1o[rt + wg * 8 + r] = v1; f2o[rt + wg * 8 + r] = v2; }
    }
}

// output attention + elu + bn + lrelu + adaptive fusion + conv + bn + lrelu
// -> yT [64][2048] bf16
__global__ void k_att_out(const float* __restrict__ WhO, const float* __restrict__ f1o,
                          const float* __restrict__ f2o, const int* __restrict__ deg,
                          const int* __restrict__ idxs, const float* __restrict__ GCNx,
                          const float* __restrict__ Wf, const float* __restrict__ bfp,
                          const float* __restrict__ cw, const float* __restrict__ cb,
                          u16* __restrict__ yT) {
    int n = blockIdx.x;
    int k = threadIdx.x;   // 64
    int d = deg[n];
    const int* row = idxs + (size_t)n * MAXDEG;
    float f1v = f1o[n];
    float mx = -1e30f;
    for (int j = 0; j < d; ++j) {
        float e = f1v + f2o[row[j]];
        e = e >= 0.f ? e : 0.2f * e;
        mx = fmaxf(mx, e);
    }
    float ssum = 0.f, acc = 0.f;
    for (int j = 0; j < d; ++j) {
        int m = row[j];
        float e = f1v + f2o[m];
        e = e >= 0.f ? e : 0.2f * e;
        float w = __expf(e - mx);
        ssum += w;
        acc += w * WhO[(size_t)m * 64 + k];
    }
    float v = acc / ssum;
    v = v > 0.f ? v : __expf(v) - 1.f;   // elu
    v *= BNF;
    float gat = v >= 0.f ? v : 0.01f * v;
    float g = GCNx[(size_t)n * 64 + k];
    float mn = fminf(g, gat), mxv = fmaxf(g, gat);
    float avg = g * Wf[k] + bfp[k] + gat * Wf[64 + k] + bfp[64 + k];
    float base = g + gat;
    float yv = cw[0] * (mn + base) + cw[1] * (mxv + base) + cw[2] * (avg + base) + cb[0];
    yv *= BNF;
    yv = yv >= 0.f ? yv : 0.2f * yv;
    yT[k * 2048 + n] = f2bf(yv);
}

// ---------------------------------------------------------------------------
// out[i,f] = sum_n Qbf[i,n]*yT[f,n]. Tile 128i x 64f, K-step 64, dbuf LDS,
// counted vmcnt, grid 512, direct stores.
// ---------------------------------------------------------------------------
__global__ __launch_bounds__(256, 2) void k_final(const u16* __restrict__ Qbf,
                                                  const u16* __restrict__ yT,
                                                  float* __restrict__ out) {
    __shared__ __align__(16) u16 Aq[2][128 * 64];   // 16 KB per buf
    __shared__ __align__(16) u16 By[2][64 * 64];    // 8 KB per buf
    const int i0 = blockIdx.x * 128;
    const int t = threadIdx.x, w = t >> 6, l = t & 63;
    // staging: seg = 8 rows x 64 u16 (1KB). lane l -> row l>>3, slot l&7.
    const int lrow = l >> 3;
    const int scol = (((l & 7) ^ ((l >> 3) & 7)) << 3);
    f32x4 acc[2][4];
#pragma unroll
    for (int a = 0; a < 2; ++a)
#pragma unroll
        for (int b = 0; b < 4; ++b) acc[a][b] = (f32x4){0.f, 0.f, 0.f, 0.f};

#define STAGE_F(buf, step)                                                          \
    {                                                                               \
        const size_t kc = (size_t)(step) * 64 + scol;                               \
        for (int s = w; s < 16; s += 4)                                             \
            gload16(&Qbf[(size_t)(i0 + s * 8 + lrow) * 2048 + kc],                  \
                    &Aq[buf][s * 512]);                                             \
        for (int s = w; s < 8; s += 4)                                              \
            gload16(&yT[(size_t)(s * 8 + lrow) * 2048 + kc],                        \
                    &By[buf][s * 512]);                                             \
    }

    STAGE_F(0, 0);
    for (int step = 0; step < 32; ++step) {
        const int cur = step & 1;
        if (step + 1 < 32) {
            STAGE_F(cur ^ 1, step + 1);
            asm volatile("s_waitcnt vmcnt(6)" ::: "memory");
        } else {
            asm volatile("s_waitcnt vmcnt(0)" ::: "memory");
        }
        __builtin_amdgcn_s_barrier();

        const u16* Ab = Aq[cur];
        const u16* Bb = By[cur];
#pragma unroll
        for (int sub = 0; sub < 2; ++sub) {
            const int c8 = sub * 4 + (l >> 4);       // logical 8-u16 chunk 0..7
            Frag a[2];
#pragma unroll
            for (int it = 0; it < 2; ++it) {
                const int r = w * 32 + it * 16 + (l & 15);
                a[it].v = *(const short8*)&Ab[r * 64 + ((c8 ^ (r & 7)) << 3)];
            }
#pragma unroll
            for (int ft = 0; ft < 4; ++ft) {
                const int rb = ft * 16 + (l & 15);
                Frag b;
                b.v = *(const short8*)&Bb[rb * 64 + ((c8 ^ (rb & 7)) << 3)];
#pragma unroll
                for (int it = 0; it < 2; ++it)
                    acc[it][ft] = __builtin_amdgcn_mfma_f32_16x16x32_bf16(
                        a[it].v, b.v, acc[it][ft], 0, 0, 0);
            }
        }
        asm volatile("s_waitcnt lgkmcnt(0)" ::: "memory");
        __builtin_amdgcn_s_barrier();
    }
#undef STAGE_F
#pragma unroll
    for (int it = 0; it < 2; ++it)
#pragma unroll
        for (int ft = 0; ft < 4; ++ft) {
            const int i = i0 + w * 32 + it * 16 + ((l >> 4) << 2);
            const int f = ft * 16 + (l & 15);
#pragma unroll
            for (int r = 0; r < 4; ++r)
                out[(size_t)(i + r) * 64 + f] = acc[it][ft][r];
        }
}

extern "C" void kernel_launch(void* const* d_in, const int* in_sizes, int n_in,
                              void* d_out, int out_size, void* d_ws, size_t ws_size,
                              hipStream_t stream) {
    const float* x     = (const float*)d_in[0];
    const float* adj   = (const float*)d_in[1];
    const float* Q     = (const float*)d_in[2];
    const float* g1aW  = (const float*)d_in[3];
    const float* g1ab  = (const float*)d_in[4];
    const float* g1bW  = (const float*)d_in[5];
    const float* g1bb  = (const float*)d_in[6];
    const float* g2aW  = (const float*)d_in[7];
    const float* g2ab  = (const float*)d_in[8];
    const float* g2bW  = (const float*)d_in[9];
    const float* g2bb  = (const float*)d_in[10];
    const float* gatW  = (const float*)d_in[11];
    const float* gata  = (const float*)d_in[12];
    const float* outW  = (const float*)d_in[13];
    const float* outa  = (const float*)d_in[14];
    const float* Wf    = (const float*)d_in[15];
    const float* bfp   = (const float*)d_in[16];
    const float* convw = (const float*)d_in[17];
    const float* convb = (const float*)d_in[18];

    float* ws   = (float*)d_ws;
    float* S    = ws;
    float* cs   = ws + 409600;
    float* xn   = ws + 411648;
    float* xg   = ws + 821248;
    float* xg2  = ws + 1230848;
    float* hbuf = ws + 1640448;
    float* zbuf = ws + 2050048;
    float* WhO  = ws + 2312192;
    float* GCNx = ws + 2443264;
    float* f1   = ws + 2836480;
    float* f2   = ws + 2844672;
    float* f1o  = ws + 2852864;
    float* f2o  = ws + 2854912;
    int*   deg  = (int*)(ws + 2856960);
    int*   idxs = (int*)(ws + 2859008);
    u16*   yT   = (u16*)(ws + 1640448);           // reuses hbuf region
    float* csPart = ws + 3000000;                 // 512*2048 f32
    u16*   QbfT   = (u16*)(ws + 4200000);         // 2048*65536 u16 = 256MB
    u16*   Qbf    = (u16*)(ws + 71308864);        // 65536*2048 u16 = 256MB
    u16*   xfT    = (u16*)(ws + 138417728);       // 208*65536 u16 (8 pad rows)

    float* out  = (float*)d_out;
    float* WhB  = out;             // 2048*512 scratch inside d_out
    float* hcat = out + 1048576;   // 2048*512 scratch inside d_out

    // zero atomic target S
    hipMemsetAsync(S, 0, 409600 * sizeof(float), stream);

    // ---- bf16 conversion passes ----
    k_conv<<<dim3(512, 16), 256, 0, stream>>>(Q, Qbf, QbfT, csPart);
    k_convX<<<512, 256, 0, stream>>>(x, xfT);
    k_csum<<<8, 256, 0, stream>>>(csPart, cs);

    k_bigS<<<512, 256, 0, stream>>>(QbfT, xfT, S);
    k_norm<<<(N * C + 255) / 256, 256, 0, stream>>>(S, cs, xn, xg);
    k_csr<<<N / 4, 256, 0, stream>>>(adj, deg, idxs);

    // ---- GCN branch ----
    k_mm<<<dim3(64, 2, 1), 256, 0, stream>>>(xg, g1aW, hbuf, 200, 128, 128, 0, 0, BNF);
    k_spmm<<<N, 128, 0, stream>>>(hbuf, deg, idxs, g1ab, nullptr, zbuf, 128, 1.f, 1);
    k_mm<<<dim3(64, 4, 1), 256, 0, stream>>>(zbuf, g1bW, hbuf, 128, 200, 200, 0, 0, BNF);
    k_spmm<<<N, 128, 0, stream>>>(hbuf, deg, idxs, g1bb, xg, xg2, 200, BNF, 1);
    k_mm<<<dim3(64, 2, 1), 256, 0, stream>>>(xg2, g2aW, hbuf, 200, 128, 128, 0, 0, BNF);
    k_spmm<<<N, 128, 0, stream>>>(hbuf, deg, idxs, g2ab, nullptr, zbuf, 128, 1.f, 1);
    k_mm<<<dim3(64, 1, 1), 256, 0, stream>>>(zbuf, g2bW, hbuf, 128, 64, 64, 0, 0, BNF);
    k_spmm<<<N, 64, 0, stream>>>(hbuf, deg, idxs, g2bb, nullptr, GCNx, 64, BNF, 1);

    // ---- GAT branch ----
    k_gatWh<<<dim3(64, 4), 256, 0, stream>>>(xn, gatW, gata, WhB, f1, f2);
    k_att_head<<<dim3(N, 4), 128, 0, stream>>>(WhB, f1, f2, deg, idxs, hcat);
    k_mmO<<<64, 256, 0, stream>>>(hcat, outW, outa, WhO, f1o, f2o);

    // ---- output attention + fusion -> yT ----
    k_att_out<<<N, 64, 0, stream>>>(WhO, f1o, f2o, deg, idxs, GCNx,
                                    Wf, bfp, convw, convb, yT);

    // ---- final projection (overwrites WhB/hcat scratch in d_out) ----
    k_final<<<512, 256, 0, stream>>>(Qbf, yT, out);
}

// Round 8
// 726.421 us; speedup vs baseline: 1.2972x; 1.2718x over previous
//
#include <hip/hip_runtime.h>
#include <math.h>

#define BNF 0.9999950000374997f

constexpr int N    = 2048;
constexpr int C    = 200;
constexpr int HW   = 65536;
constexpr int MAXDEG = 96;

typedef unsigned short u16;
typedef __attribute__((ext_vector_type(8))) short short8;
typedef __attribute__((ext_vector_type(4))) float f32x4;

union Frag  { short8 v; ushort4 h[2]; };
union FragA { short8 v; uint2 u2[2]; };

__device__ inline u16 f2bf(float x) {
    unsigned int u = __float_as_uint(x);
    unsigned int r = (u + 0x7fffu + ((u >> 16) & 1u)) >> 16;
    return (u16)r;
}

// async global->LDS, 16B per lane, wave-uniform LDS base, per-lane global addr
__device__ __forceinline__ void gload16(const void* g, void* l) {
    __builtin_amdgcn_global_load_lds(
        (const __attribute__((address_space(1))) unsigned int*)g,
        (__attribute__((address_space(3))) unsigned int*)l, 16, 0, 0);
}

// ---------------------------------------------------------------------------
// xf [65536][200] f32 -> xfT [256][65536] bf16 (rows 200..255 zeroed)
// ---------------------------------------------------------------------------
__global__ __launch_bounds__(256) void k_convX(const float* __restrict__ xf,
                                               u16* __restrict__ xfT) {
    __shared__ __align__(16) u16 T2[200][140];
    const int i0 = blockIdx.x * 128;
    const int t = threadIdx.x;
    for (int p = 0; p < 25; ++p) {
        int idx = p * 256 + t;
        int il = idx / 50, cq = idx % 50;
        float4 v = *(const float4*)&xf[(size_t)(i0 + il) * 200 + cq * 4];
        T2[cq * 4 + 0][il] = f2bf(v.x);
        T2[cq * 4 + 1][il] = f2bf(v.y);
        T2[cq * 4 + 2][il] = f2bf(v.z);
        T2[cq * 4 + 3][il] = f2bf(v.w);
    }
    __syncthreads();
    for (int p = 0; p < 13; ++p) {
        int c = p * 16 + (t >> 4);
        if (c < 200) {
            int io = (t & 15) * 8;
            u16* dst = &xfT[(size_t)c * 65536 + i0 + io];
            *(ushort4*)&dst[0] = *(const ushort4*)&T2[c][io];
            *(ushort4*)&dst[4] = *(const ushort4*)&T2[c][io + 4];
        }
    }
    // zero rows 200..255 for this i-stripe (56 rows x 16 ushort8 chunks)
    ushort4 z4 = {0, 0, 0, 0};
    for (int idx = t; idx < 56 * 16; idx += 256) {
        int r = 200 + (idx >> 4), io = (idx & 15) * 8;
        u16* dst = &xfT[(size_t)r * 65536 + i0 + io];
        *(ushort4*)&dst[0] = z4;
        *(ushort4*)&dst[4] = z4;
    }
}

// ---------------------------------------------------------------------------
// Fused conversion + S-partial GEMM:
//   S_part[ks][n][c] = sum_{i in slab ks} Q[i][n] * xf[i][c]
//   Qbf[i][n] = bf16(Q[i][n]);  csPart[ks][n] = sum_{i in slab} Q[i][n]
// grid 512 flat (16 nt x 32 ks, XCD remap), block 256 (4 waves), K-step 32.
// A: f32 regs -> cvt -> [n][k] LDS (pad 34, odd-row +2 shift, 2-way-free).
// B: gload_lds dbuf, 4 gloads/wave static, XOR-swizzled (round-7 proven).
// ---------------------------------------------------------------------------
__global__ __launch_bounds__(256, 2) void k_bigS(const float* __restrict__ Q,
                                                 const u16* __restrict__ xfT,
                                                 u16* __restrict__ Qbf,
                                                 float* __restrict__ S_part,
                                                 float* __restrict__ csPart) {
    __shared__ __align__(16) u16 Bt[2][256 * 32];   // 16 KB per buf
    __shared__ __align__(16) u16 At[128 * 34];      // 8.7 KB
    const int bid = blockIdx.x;
    const int xcd = bid & 7, jj = bid >> 3;
    const int nt_b = jj & 15;
    const int ks_b = ((jj >> 4) << 3) + xcd;        // same-slab blocks -> same XCD
    const int n0 = nt_b * 128;
    const size_t i0 = (size_t)ks_b * 2048;          // k-slab base (i rows)
    const int t = threadIdx.x, w = t >> 6, l = t & 63;
    const int ct0 = (w == 0) ? 0 : (4 + (w - 1) * 3);
    const int nct = (w == 0) ? 4 : 3;
    // B staging lane mapping (16-row segs, inverse-swizzled source chunk)
    const int lrowB = l >> 2;
    const int scolB = (((l & 3) ^ ((l >> 3) & 3)) << 3);
    // A lane mapping: nq -> n-quad, kp -> k row-pair
    const int nq = t & 15;
    const int kp = t >> 4;

    f32x4 acc[8][4];
#pragma unroll
    for (int a = 0; a < 8; ++a)
#pragma unroll
        for (int b = 0; b < 4; ++b) acc[a][b] = (f32x4){0.f, 0.f, 0.f, 0.f};
    float csum[8] = {0.f, 0.f, 0.f, 0.f, 0.f, 0.f, 0.f, 0.f};

    float4 a0q[2], a0r[2], a1q[2], a1r[2];

#define ISSUE_B(PAR, STEP)                                                      \
    {                                                                           \
        const size_t kc = i0 + (size_t)(STEP) * 32 + scolB;                     \
        _Pragma("unroll")                                                       \
        for (int s = 0; s < 4; ++s) {                                           \
            const int seg = w + s * 4;                                          \
            gload16(&xfT[(size_t)(seg * 16 + lrowB) * 65536 + kc],              \
                    &Bt[PAR][seg * 512]);                                       \
        }                                                                       \
    }

#define LOAD_A(AQ, AR, STEP)                                                    \
    {                                                                           \
        const size_t r0 = (i0 + (size_t)(STEP) * 32 + kp * 2) * 2048;           \
        _Pragma("unroll")                                                       \
        for (int h = 0; h < 2; ++h) {                                           \
            const float* qp = &Q[r0 + n0 + h * 64 + nq * 4];                    \
            AQ[h] = *(const float4*)qp;                                         \
            AR[h] = *(const float4*)(qp + 2048);                                \
        }                                                                       \
    }

#define WRITE_A(AQ, AR, STEP)                                                   \
    {                                                                           \
        const size_t r0 = i0 + (size_t)(STEP) * 32 + kp * 2;                    \
        _Pragma("unroll")                                                       \
        for (int h = 0; h < 2; ++h) {                                           \
            const float* ca = (const float*)&AQ[h];                             \
            const float* cb = (const float*)&AR[h];                             \
            ushort4 s0, s1;                                                     \
            u16* q0 = (u16*)&s0; u16* q1 = (u16*)&s1;                           \
            _Pragma("unroll")                                                   \
            for (int j = 0; j < 4; ++j) {                                       \
                const int n_ = nq * 4 + h * 64 + j;                             \
                ushort2 p2;                                                     \
                p2.x = f2bf(ca[j]); p2.y = f2bf(cb[j]);                         \
                *(ushort2*)&At[n_ * 34 + ((n_ & 1) << 1) + kp * 2] = p2;        \
                csum[h * 4 + j] += ca[j] + cb[j];                               \
                q0[j] = p2.x; q1[j] = p2.y;                                     \
            }                                                                   \
            *(ushort4*)&Qbf[(size_t)r0 * 2048 + n0 + h * 64 + nq * 4] = s0;     \
            *(ushort4*)&Qbf[(size_t)(r0 + 1) * 2048 + n0 + h * 64 + nq * 4] = s1; \
        }                                                                       \
    }

#define MFMA_PHASE(PAR)                                                         \
    {                                                                           \
        const u16* Bb = Bt[PAR];                                                \
        const int g = l >> 4;                                                   \
        FragA af[8];                                                            \
        _Pragma("unroll")                                                       \
        for (int nt = 0; nt < 8; ++nt) {                                        \
            const int r = nt * 16 + (l & 15);                                   \
            const int ab = r * 34 + ((r & 1) << 1) + g * 8;                     \
            af[nt].u2[0] = *(const uint2*)&At[ab];                              \
            af[nt].u2[1] = *(const uint2*)&At[ab + 4];                          \
        }                                                                       \
        _Pragma("unroll")                                                       \
        for (int c = 0; c < 4; ++c) {                                           \
            if (c < nct) {                                                      \
                const int rb = (ct0 + c) * 16 + (l & 15);                       \
                Frag bf;                                                        \
                bf.v = *(const short8*)&Bb[rb * 32 + ((g ^ ((rb >> 1) & 3)) << 3)]; \
                _Pragma("unroll")                                               \
                for (int nt = 0; nt < 8; ++nt)                                  \
                    acc[nt][c] = __builtin_amdgcn_mfma_f32_16x16x32_bf16(       \
                        af[nt].v, bf.v, acc[nt][c], 0, 0, 0);                   \
            }                                                                   \
        }                                                                       \
    }

#define STEPBODY(STEP, PAR, NPAR, CQ, CR, NQr, NRr, COND)                       \
    {                                                                           \
        if (COND) ISSUE_B(NPAR, (STEP) + 1);                                    \
        WRITE_A(CQ, CR, STEP);                                                  \
        if (COND) LOAD_A(NQr, NRr, (STEP) + 1);                                 \
        asm volatile("s_waitcnt lgkmcnt(0)" ::: "memory");                      \
        __builtin_amdgcn_s_barrier();                                           \
        if (COND) { asm volatile("s_waitcnt vmcnt(12)" ::: "memory"); }         \
        else      { asm volatile("s_waitcnt vmcnt(0)"  ::: "memory"); }         \
        MFMA_PHASE(PAR);                                                        \
        __builtin_amdgcn_s_barrier();                                           \
    }

    // prologue
    ISSUE_B(0, 0);
    LOAD_A(a0q, a0r, 0);

    for (int s2 = 0; s2 < 32; ++s2) {
        STEPBODY(s2 * 2,     0, 1, a0q, a0r, a1q, a1r, true);
        STEPBODY(s2 * 2 + 1, 1, 0, a1q, a1r, a0q, a0r, (s2 < 31));
    }
#undef STEPBODY
#undef MFMA_PHASE
#undef WRITE_A
#undef LOAD_A
#undef ISSUE_B

    // ---- epilogue: colsum reduce (reuse At as float scratch) ----
    __syncthreads();
    float* csF = (float*)At;
#pragma unroll
    for (int h = 0; h < 2; ++h)
#pragma unroll
        for (int j = 0; j < 4; ++j)
            csF[kp * 128 + nq * 4 + h * 64 + j] = csum[h * 4 + j];
    __syncthreads();
    if (t < 128) {
        float s = 0.f;
#pragma unroll
        for (int g2 = 0; g2 < 16; ++g2) s += csF[g2 * 128 + t];
        csPart[(size_t)ks_b * 2048 + n0 + t] = s;
    }
    // ---- S partial stores (non-atomic) ----
    float* Sp = S_part + (size_t)ks_b * 409600;
#pragma unroll
    for (int nt = 0; nt < 8; ++nt)
#pragma unroll
        for (int c = 0; c < 4; ++c) {
            if (c < nct) {
                const int cc = (ct0 + c) * 16 + (l & 15);
                if (cc < 200) {
                    const int nbase = n0 + nt * 16 + ((l >> 4) << 2);
#pragma unroll
                    for (int r = 0; r < 4; ++r)
                        Sp[(size_t)(nbase + r) * 200 + cc] = acc[nt][c][r];
                }
            }
        }
}

// cs[n] = sum_ks csPart[ks][n]
__global__ void k_csum(const float* __restrict__ csPart, float* __restrict__ cs) {
    int n = blockIdx.x * 256 + threadIdx.x;
    float s = 0.f;
#pragma unroll 8
    for (int p = 0; p < 32; ++p) s += csPart[(size_t)p * 2048 + n];
    cs[n] = s;
}

// xn = BN * (sum_ks S_part) / cs ; xg = BN * xn
__global__ void k_redS(const float* __restrict__ S_part, const float* __restrict__ cs,
                       float* __restrict__ xn, float* __restrict__ xg) {
    int i = blockIdx.x * 256 + threadIdx.x;
    if (i >= N * C) return;
    float s = 0.f;
#pragma unroll 8
    for (int p = 0; p < 32; ++p) s += S_part[(size_t)p * 409600 + i];
    int n = i / C;
    float v = BNF * s / cs[n];
    xn[i] = v;
    xg[i] = BNF * v;
}

// CSR build
__global__ void k_csr(const float* __restrict__ adj, int* __restrict__ deg,
                      int* __restrict__ idxs) {
    int w = threadIdx.x >> 6, lane = threadIdx.x & 63;
    int n = blockIdx.x * 4 + w;
    const float* row = adj + (size_t)n * N;
    int base = 0;
    for (int c = 0; c < N; c += 64) {
        float v = row[c + lane];
        bool p = v > 0.f;
        unsigned long long m = __ballot(p);
        int pos = __popcll(m & ((1ull << lane) - 1ull));
        if (p && (base + pos) < MAXDEG) idxs[(size_t)n * MAXDEG + base + pos] = c + lane;
        base += __popcll(m);
    }
    if (lane == 0) deg[n] = base < MAXDEG ? base : MAXDEG;
}

// generic small dense mm (GCN branch)
__global__ __launch_bounds__(256) void k_mm(const float* __restrict__ A,
                                            const float* __restrict__ W,
                                            float* __restrict__ Cc,
                                            int K, int Wout, int ostride,
                                            int zc_off, int zw_str, float scale) {
    __shared__ float ldsA[32][33];
    __shared__ float ldsW[32][64];
    const int rt = blockIdx.x * 32;
    const int ct = blockIdx.y * 64;
    const int z  = blockIdx.z;
    const float* Wp = W + (size_t)z * zw_str;
    const int coff = z * zc_off;
    const int t = threadIdx.x;
    const int lane = t & 63, wg = t >> 6;
    float acc[8];
#pragma unroll
    for (int r = 0; r < 8; ++r) acc[r] = 0.f;

    for (int k0 = 0; k0 < K; k0 += 32) {
        for (int idx = t; idx < 32 * 32; idx += 256) {
            int r = idx >> 5, kk = idx & 31;
            int k = k0 + kk;
            ldsA[r][kk] = (k < K) ? A[(size_t)(rt + r) * K + k] : 0.f;
        }
        for (int idx = t; idx < 32 * 64; idx += 256) {
            int kk = idx >> 6, c = idx & 63;
            int k = k0 + kk, cg = ct + c;
            ldsW[kk][c] = (k < K && cg < Wout) ? Wp[(size_t)k * Wout + cg] : 0.f;
        }
        __syncthreads();
#pragma unroll 8
        for (int kk = 0; kk < 32; ++kk) {
            float wv = ldsW[kk][lane];
#pragma unroll
            for (int r = 0; r < 8; ++r) acc[r] += ldsA[wg * 8 + r][kk] * wv;
        }
        __syncthreads();
    }
    int cg = ct + lane;
    if (cg < Wout) {
#pragma unroll
        for (int r = 0; r < 8; ++r)
            Cc[(size_t)(rt + wg * 8 + r) * ostride + coff + cg] = scale * acc[r];
    }
}

// out[n,k] = (res?res:0) + act( s*(sum_nbr h + bias) )
__global__ void k_spmm(const float* __restrict__ h, const int* __restrict__ deg,
                       const int* __restrict__ idxs, const float* __restrict__ bias,
                       const float* __restrict__ res, float* __restrict__ out,
                       int W, float s, int act) {
    int n = blockIdx.x;
    int d = deg[n];
    const int* row = idxs + (size_t)n * MAXDEG;
    int k0 = threadIdx.x;
    int k1 = threadIdx.x + 128;
    float a0 = 0.f, a1 = 0.f;
    for (int j = 0; j < d; ++j) {
        const float* hr = h + (size_t)row[j] * W;
        a0 += hr[k0];
        if (k1 < W) a1 += hr[k1];
    }
    {
        float v = s * (a0 + bias[k0]);
        if (act) v = v >= 0.f ? v : 0.01f * v;
        if (res) v += res[(size_t)n * W + k0];
        out[(size_t)n * W + k0] = v;
    }
    if (k1 < W) {
        float v = s * (a1 + bias[k1]);
        if (act) v = v >= 0.f ? v : 0.01f * v;
        if (res) v += res[(size_t)n * W + k1];
        out[(size_t)n * W + k1] = v;
    }
}

// Wh = xn @ gat_W[h] (32x128 per block) + f1/f2 row-dot epilogue
__global__ __launch_bounds__(256) void k_gatWh(const float* __restrict__ xn,
                                               const float* __restrict__ gatW,
                                               const float* __restrict__ gata,
                                               float* __restrict__ WhB,
                                               float* __restrict__ f1,
                                               float* __restrict__ f2) {
    __shared__ float ldsA[32][33];
    __shared__ float ldsW[32][128];
    __shared__ float ldsWh[32][129];
    const int rt = blockIdx.x * 32;
    const int h  = blockIdx.y;
    const float* Wp = gatW + (size_t)h * 200 * 128;
    const int t = threadIdx.x;
    const int col = t & 127, rg = t >> 7;
    float acc[16];
#pragma unroll
    for (int r = 0; r < 16; ++r) acc[r] = 0.f;

    for (int k0 = 0; k0 < 200; k0 += 32) {
        for (int idx = t; idx < 32 * 32; idx += 256) {
            int r = idx >> 5, kk = idx & 31;
            int k = k0 + kk;
            ldsA[r][kk] = (k < 200) ? xn[(size_t)(rt + r) * 200 + k] : 0.f;
        }
        for (int idx = t; idx < 32 * 128; idx += 256) {
            int kk = idx >> 7, c = idx & 127;
            int k = k0 + kk;
            ldsW[kk][c] = (k < 200) ? Wp[(size_t)k * 128 + c] : 0.f;
        }
        __syncthreads();
#pragma unroll 8
        for (int kk = 0; kk < 32; ++kk) {
            float wv = ldsW[kk][col];
#pragma unroll
            for (int r = 0; r < 16; ++r) acc[r] += ldsA[rg * 16 + r][kk] * wv;
        }
        __syncthreads();
    }
#pragma unroll
    for (int r = 0; r < 16; ++r) {
        ldsWh[rg * 16 + r][col] = acc[r];
        WhB[(size_t)(rt + rg * 16 + r) * 512 + h * 128 + col] = acc[r];
    }
    __syncthreads();
    int row = t >> 3, p = t & 7;
    const float* a = gata + h * 256;
    float s1 = 0.f, s2 = 0.f;
#pragma unroll
    for (int j = 0; j < 16; ++j) {
        int c = p * 16 + j;
        float v = ldsWh[row][c];
        s1 += v * a[c]; s2 += v * a[128 + c];
    }
    s1 += __shfl_xor(s1, 1); s1 += __shfl_xor(s1, 2); s1 += __shfl_xor(s1, 4);
    s2 += __shfl_xor(s2, 1); s2 += __shfl_xor(s2, 2); s2 += __shfl_xor(s2, 4);
    if (p == 0) { f1[h * N + rt + row] = s1; f2[h * N + rt + row] = s2; }
}

// per-head masked-softmax attention + ELU -> hcat[n, h*128+k]
__global__ void k_att_head(const float* __restrict__ WhB, const float* __restrict__ f1,
                           const float* __restrict__ f2, const int* __restrict__ deg,
                           const int* __restrict__ idxs, float* __restrict__ hcat) {
    int n = blockIdx.x, h = blockIdx.y;
    int k = threadIdx.x;
    int d = deg[n];
    const int* row = idxs + (size_t)n * MAXDEG;
    float f1v = f1[h * N + n];
    const float* f2h = f2 + h * N;
    float mx = -1e30f;
    for (int j = 0; j < d; ++j) {
        float e = f1v + f2h[row[j]];
        e = e >= 0.f ? e : 0.2f * e;
        mx = fmaxf(mx, e);
    }
    float ssum = 0.f, acc = 0.f;
    for (int j = 0; j < d; ++j) {
        int m = row[j];
        float e = f1v + f2h[m];
        e = e >= 0.f ? e : 0.2f * e;
        float w = __expf(e - mx);
        ssum += w;
        acc += w * WhB[(size_t)m * 512 + h * 128 + k];
    }
    float v = acc / ssum;
    v = v > 0.f ? v : __expf(v) - 1.f;
    hcat[(size_t)n * 512 + h * 128 + k] = v;
}

// WhO = hcat @ outW (32x64, K=512) + f1o/f2o row-dot epilogue
__global__ __launch_bounds__(256) void k_mmO(const float* __restrict__ hcat,
                                             const float* __restrict__ outW,
                                             const float* __restrict__ outa,
                                             float* __restrict__ WhO,
                                             float* __restrict__ f1o,
                                             float* __restrict__ f2o) {
    __shared__ float ldsA[32][33];
    __shared__ float ldsW[32][64];
    const int rt = blockIdx.x * 32;
    const int t = threadIdx.x;
    const int lane = t & 63, wg = t >> 6;
    float acc[8];
#pragma unroll
    for (int r = 0; r < 8; ++r) acc[r] = 0.f;

    for (int k0 = 0; k0 < 512; k0 += 32) {
        for (int idx = t; idx < 32 * 32; idx += 256) {
            int r = idx >> 5, kk = idx & 31;
            ldsA[r][kk] = hcat[(size_t)(rt + r) * 512 + k0 + kk];
        }
        for (int idx = t; idx < 32 * 64; idx += 256) {
            int kk = idx >> 6, c = idx & 63;
            ldsW[kk][c] = outW[(size_t)(k0 + kk) * 64 + c];
        }
        __syncthreads();
#pragma unroll 8
        for (int kk = 0; kk < 32; ++kk) {
            float wv = ldsW[kk][lane];
#pragma unroll
            for (int r = 0; r < 8; ++r) acc[r] += ldsA[wg * 8 + r][kk] * wv;
        }
        __syncthreads();
    }
#pragma unroll
    for (int r = 0; r < 8; ++r)
        WhO[(size_t)(rt + wg * 8 + r) * 64 + lane] = acc[r];
#pragma unroll
    for (int r = 0; r < 8; ++r) {
        float v1 = acc[r] * outa[lane];
        float v2 = acc[r] * outa[64 + lane];
#pragma unroll
        for (int off = 32; off; off >>= 1) {
            v1 += __shfl_down(v1, off);
            v2 += __shfl_down(v2, off);
        }
        if (lane == 0) { f1o[rt + wg * 8 + r] = v1; f2o[rt + wg * 8 + r] = v2; }
    }
}

// output attention + elu + bn + lrelu + adaptive fusion + conv + bn + lrelu
// -> yT [64][2048] bf16
__global__ void k_att_out(const float* __restrict__ WhO, const float* __restrict__ f1o,
                          const float* __restrict__ f2o, const int* __restrict__ deg,
                          const int* __restrict__ idxs, const float* __restrict__ GCNx,
                          const float* __restrict__ Wf, const float* __restrict__ bfp,
                          const float* __restrict__ cw, const float* __restrict__ cb,
                          u16* __restrict__ yT) {
    int n = blockIdx.x;
    int k = threadIdx.x;   // 64
    int d = deg[n];
    const int* row = idxs + (size_t)n * MAXDEG;
    float f1v = f1o[n];
    float mx = -1e30f;
    for (int j = 0; j < d; ++j) {
        float e = f1v + f2o[row[j]];
        e = e >= 0.f ? e : 0.2f * e;
        mx = fmaxf(mx, e);
    }
    float ssum = 0.f, acc = 0.f;
    for (int j = 0; j < d; ++j) {
        int m = row[j];
        float e = f1v + f2o[m];
        e = e >= 0.f ? e : 0.2f * e;
        float w = __expf(e - mx);
        ssum += w;
        acc += w * WhO[(size_t)m * 64 + k];
    }
    float v = acc / ssum;
    v = v > 0.f ? v : __expf(v) - 1.f;   // elu
    v *= BNF;
    float gat = v >= 0.f ? v : 0.01f * v;
    float g = GCNx[(size_t)n * 64 + k];
    float mn = fminf(g, gat), mxv = fmaxf(g, gat);
    float avg = g * Wf[k] + bfp[k] + gat * Wf[64 + k] + bfp[64 + k];
    float base = g + gat;
    float yv = cw[0] * (mn + base) + cw[1] * (mxv + base) + cw[2] * (avg + base) + cb[0];
    yv *= BNF;
    yv = yv >= 0.f ? yv : 0.2f * yv;
    yT[k * 2048 + n] = f2bf(yv);
}

// ---------------------------------------------------------------------------
// out[i,f] = sum_n Qbf[i,n]*yT[f,n]. Tile 128i x 64f, K-step 64, dbuf LDS,
// counted vmcnt, grid 512, direct stores.  (round-7 proven)
// ---------------------------------------------------------------------------
__global__ __launch_bounds__(256, 2) void k_final(const u16* __restrict__ Qbf,
                                                  const u16* __restrict__ yT,
                                                  float* __restrict__ out) {
    __shared__ __align__(16) u16 Aq[2][128 * 64];
    __shared__ __align__(16) u16 By[2][64 * 64];
    const int i0 = blockIdx.x * 128;
    const int t = threadIdx.x, w = t >> 6, l = t & 63;
    const int lrow = l >> 3;
    const int scol = (((l & 7) ^ ((l >> 3) & 7)) << 3);
    f32x4 acc[2][4];
#pragma unroll
    for (int a = 0; a < 2; ++a)
#pragma unroll
        for (int b = 0; b < 4; ++b) acc[a][b] = (f32x4){0.f, 0.f, 0.f, 0.f};

#define STAGE_F(buf, step)                                                          \
    {                                                                               \
        const size_t kc = (size_t)(step) * 64 + scol;                               \
        for (int s = w; s < 16; s += 4)                                             \
            gload16(&Qbf[(size_t)(i0 + s * 8 + lrow) * 2048 + kc],                  \
                    &Aq[buf][s * 512]);                                             \
        for (int s = w; s < 8; s += 4)                                              \
            gload16(&yT[(size_t)(s * 8 + lrow) * 2048 + kc],                        \
                    &By[buf][s * 512]);                                             \
    }

    STAGE_F(0, 0);
    for (int step = 0; step < 32; ++step) {
        const int cur = step & 1;
        if (step + 1 < 32) {
            STAGE_F(cur ^ 1, step + 1);
            asm volatile("s_waitcnt vmcnt(6)" ::: "memory");
        } else {
            asm volatile("s_waitcnt vmcnt(0)" ::: "memory");
        }
        __builtin_amdgcn_s_barrier();

        const u16* Ab = Aq[cur];
        const u16* Bb = By[cur];
#pragma unroll
        for (int sub = 0; sub < 2; ++sub) {
            const int c8 = sub * 4 + (l >> 4);
            Frag a[2];
#pragma unroll
            for (int it = 0; it < 2; ++it) {
                const int r = w * 32 + it * 16 + (l & 15);
                a[it].v = *(const short8*)&Ab[r * 64 + ((c8 ^ (r & 7)) << 3)];
            }
#pragma unroll
            for (int ft = 0; ft < 4; ++ft) {
                const int rb = ft * 16 + (l & 15);
                Frag b;
                b.v = *(const short8*)&Bb[rb * 64 + ((c8 ^ (rb & 7)) << 3)];
#pragma unroll
                for (int it = 0; it < 2; ++it)
                    acc[it][ft] = __builtin_amdgcn_mfma_f32_16x16x32_bf16(
                        a[it].v, b.v, acc[it][ft], 0, 0, 0);
            }
        }
        asm volatile("s_waitcnt lgkmcnt(0)" ::: "memory");
        __builtin_amdgcn_s_barrier();
    }
#undef STAGE_F
#pragma unroll
    for (int it = 0; it < 2; ++it)
#pragma unroll
        for (int ft = 0; ft < 4; ++ft) {
            const int i = i0 + w * 32 + it * 16 + ((l >> 4) << 2);
            const int f = ft * 16 + (l & 15);
#pragma unroll
            for (int r = 0; r < 4; ++r)
                out[(size_t)(i + r) * 64 + f] = acc[it][ft][r];
        }
}

extern "C" void kernel_launch(void* const* d_in, const int* in_sizes, int n_in,
                              void* d_out, int out_size, void* d_ws, size_t ws_size,
                              hipStream_t stream) {
    const float* x     = (const float*)d_in[0];
    const float* adj   = (const float*)d_in[1];
    const float* Q     = (const float*)d_in[2];
    const float* g1aW  = (const float*)d_in[3];
    const float* g1ab  = (const float*)d_in[4];
    const float* g1bW  = (const float*)d_in[5];
    const float* g1bb  = (const float*)d_in[6];
    const float* g2aW  = (const float*)d_in[7];
    const float* g2ab  = (const float*)d_in[8];
    const float* g2bW  = (const float*)d_in[9];
    const float* g2bb  = (const float*)d_in[10];
    const float* gatW  = (const float*)d_in[11];
    const float* gata  = (const float*)d_in[12];
    const float* outW  = (const float*)d_in[13];
    const float* outa  = (const float*)d_in[14];
    const float* Wf    = (const float*)d_in[15];
    const float* bfp   = (const float*)d_in[16];
    const float* convw = (const float*)d_in[17];
    const float* convb = (const float*)d_in[18];

    float* ws   = (float*)d_ws;
    float* cs   = ws + 409600;
    float* xn   = ws + 411648;
    float* xg   = ws + 821248;
    float* xg2  = ws + 1230848;
    float* hbuf = ws + 1640448;
    float* zbuf = ws + 2050048;
    float* WhO  = ws + 2312192;
    float* GCNx = ws + 2443264;
    float* f1   = ws + 2836480;
    float* f2   = ws + 2844672;
    float* f1o  = ws + 2852864;
    float* f2o  = ws + 2854912;
    int*   deg  = (int*)(ws + 2856960);
    int*   idxs = (int*)(ws + 2859008);
    u16*   yT   = (u16*)(ws + 1640448);           // reuses hbuf region
    float* csPart = ws + 3000000;                 // 32*2048 f32
    float* S_part = ws + 4200000;                 // 32*409600 f32 = 52 MB
    u16*   Qbf    = (u16*)(ws + 71308864);        // 65536*2048 u16 = 256MB
    u16*   xfT    = (u16*)(ws + 138417728);       // 256*65536 u16 (56 zero rows)

    float* out  = (float*)d_out;
    float* WhB  = out;             // 2048*512 scratch inside d_out
    float* hcat = out + 1048576;   // 2048*512 scratch inside d_out

    // ---- conversion + big S GEMM (fused: Q read once in f32) ----
    k_convX<<<512, 256, 0, stream>>>(x, xfT);
    k_bigS<<<512, 256, 0, stream>>>(Q, xfT, Qbf, S_part, csPart);
    k_csum<<<8, 256, 0, stream>>>(csPart, cs);
    k_redS<<<(N * C + 255) / 256, 256, 0, stream>>>(S_part, cs, xn, xg);
    k_csr<<<N / 4, 256, 0, stream>>>(adj, deg, idxs);

    // ---- GCN branch ----
    k_mm<<<dim3(64, 2, 1), 256, 0, stream>>>(xg, g1aW, hbuf, 200, 128, 128, 0, 0, BNF);
    k_spmm<<<N, 128, 0, stream>>>(hbuf, deg, idxs, g1ab, nullptr, zbuf, 128, 1.f, 1);
    k_mm<<<dim3(64, 4, 1), 256, 0, stream>>>(zbuf, g1bW, hbuf, 128, 200, 200, 0, 0, BNF);
    k_spmm<<<N, 128, 0, stream>>>(hbuf, deg, idxs, g1bb, xg, xg2, 200, BNF, 1);
    k_mm<<<dim3(64, 2, 1), 256, 0, stream>>>(xg2, g2aW, hbuf, 200, 128, 128, 0, 0, BNF);
    k_spmm<<<N, 128, 0, stream>>>(hbuf, deg, idxs, g2ab, nullptr, zbuf, 128, 1.f, 1);
    k_mm<<<dim3(64, 1, 1), 256, 0, stream>>>(zbuf, g2bW, hbuf, 128, 64, 64, 0, 0, BNF);
    k_spmm<<<N, 64, 0, stream>>>(hbuf, deg, idxs, g2bb, nullptr, GCNx, 64, BNF, 1);

    // ---- GAT branch ----
    k_gatWh<<<dim3(64, 4), 256, 0, stream>>>(xn, gatW, gata, WhB, f1, f2);
    k_att_head<<<dim3(N, 4), 128, 0, stream>>>(WhB, f1, f2, deg, idxs, hcat);
    k_mmO<<<64, 256, 0, stream>>>(hcat, outW, outa, WhO, f1o, f2o);

    // ---- output attention + fusion -> yT ----
    k_att_out<<<N, 64, 0, stream>>>(WhO, f1o, f2o, deg, idxs, GCNx,
                                    Wf, bfp, convw, convb, yT);

    // ---- final projection (overwrites WhB/hcat scratch in d_out) ----
    k_final<<<512, 256, 0, stream>>>(Qbf, yT, out);
}

// Round 9
// 724.558 us; speedup vs baseline: 1.3005x; 1.0026x over previous
//
#include <hip/hip_runtime.h>
#include <math.h>

#define BNF 0.9999950000374997f

constexpr int N    = 2048;
constexpr int C    = 200;
constexpr int HW   = 65536;
constexpr int MAXDEG = 96;

typedef unsigned short u16;
typedef __attribute__((ext_vector_type(8))) short short8;
typedef __attribute__((ext_vector_type(4))) float f32x4;

union Frag  { short8 v; ushort4 h[2]; };
union FragA { short8 v; uint2 u2[2]; };

__device__ inline u16 f2bf(float x) {
    unsigned int u = __float_as_uint(x);
    unsigned int r = (u + 0x7fffu + ((u >> 16) & 1u)) >> 16;
    return (u16)r;
}

// async global->LDS, 16B per lane, wave-uniform LDS base, per-lane global addr
__device__ __forceinline__ void gload16(const void* g, void* l) {
    __builtin_amdgcn_global_load_lds(
        (const __attribute__((address_space(1))) unsigned int*)g,
        (__attribute__((address_space(3))) unsigned int*)l, 16, 0, 0);
}

// ---------------------------------------------------------------------------
// xf [65536][200] f32 -> xfT [208][65536] bf16 (rows 200..207 zeroed)
// ---------------------------------------------------------------------------
__global__ __launch_bounds__(256) void k_convX(const float* __restrict__ xf,
                                               u16* __restrict__ xfT) {
    __shared__ __align__(16) u16 T2[200][140];
    const int i0 = blockIdx.x * 128;
    const int t = threadIdx.x;
    for (int p = 0; p < 25; ++p) {
        int idx = p * 256 + t;
        int il = idx / 50, cq = idx % 50;
        float4 v = *(const float4*)&xf[(size_t)(i0 + il) * 200 + cq * 4];
        T2[cq * 4 + 0][il] = f2bf(v.x);
        T2[cq * 4 + 1][il] = f2bf(v.y);
        T2[cq * 4 + 2][il] = f2bf(v.z);
        T2[cq * 4 + 3][il] = f2bf(v.w);
    }
    __syncthreads();
    for (int p = 0; p < 13; ++p) {
        int c = p * 16 + (t >> 4);
        if (c < 200) {
            int io = (t & 15) * 8;
            u16* dst = &xfT[(size_t)c * 65536 + i0 + io];
            *(ushort4*)&dst[0] = *(const ushort4*)&T2[c][io];
            *(ushort4*)&dst[4] = *(const ushort4*)&T2[c][io + 4];
        }
    }
    ushort4 z4 = {0, 0, 0, 0};
    for (int idx = t; idx < 8 * 16; idx += 256) {
        int r = 200 + (idx >> 4), io = (idx & 15) * 8;
        u16* dst = &xfT[(size_t)r * 65536 + i0 + io];
        *(ushort4*)&dst[0] = z4;
        *(ushort4*)&dst[4] = z4;
    }
}

// ---------------------------------------------------------------------------
// Fused conversion + S-partial GEMM, 64n x 208c tile, 3 blocks/CU.
//   S_part[ks][n][c] = sum_{i in slab} Q[i][n]*xf[i][c]
//   Qbf[i][n] = bf16(Q[i][n]);  csPart[ks][n] = slab colsum
// grid 1024 flat (32 nt x 32 ks, XCD remap), block 256 (4 waves), K-step 32.
// ---------------------------------------------------------------------------
__global__ __launch_bounds__(256, 3) void k_bigS(const float* __restrict__ Q,
                                                 const u16* __restrict__ xfT,
                                                 u16* __restrict__ Qbf,
                                                 float* __restrict__ S_part,
                                                 float* __restrict__ csPart) {
    __shared__ __align__(16) u16 Bt[2][208 * 32];   // 13 KB per buf
    __shared__ __align__(16) u16 At[64 * 34];       // 4.3 KB
    const int bid = blockIdx.x;
    const int xcd = bid & 7, jb = bid >> 3;
    const int nt_b = jb & 31;
    const int ks_b = ((jb >> 5) << 3) + xcd;        // same-slab blocks -> same XCD
    const int n0 = nt_b * 64;
    const size_t i0 = (size_t)ks_b * 2048;
    const int t = threadIdx.x, w = t >> 6, l = t & 63;
    const int ct0 = (w == 0) ? 0 : (4 + (w - 1) * 3);
    const int nct = (w == 0) ? 4 : 3;
    const int lrowB = l >> 2;
    const int scolB = (((l & 3) ^ ((l >> 3) & 3)) << 3);
    const int nq = t & 15;
    const int kp = t >> 4;

    f32x4 acc[4][4];
#pragma unroll
    for (int a = 0; a < 4; ++a)
#pragma unroll
        for (int b = 0; b < 4; ++b) acc[a][b] = (f32x4){0.f, 0.f, 0.f, 0.f};
    float csum[4] = {0.f, 0.f, 0.f, 0.f};

    float4 aq0, ar0, aq1, ar1;

#define ISSUE_B(PAR, STEP)                                                      \
    {                                                                           \
        const size_t kc = i0 + (size_t)(STEP) * 32 + scolB;                     \
        for (int s = w; s < 13; s += 4)                                         \
            gload16(&xfT[(size_t)(s * 16 + lrowB) * 65536 + kc],                \
                    &Bt[PAR][s * 512]);                                         \
    }

#define LOAD_A(AQ, AR, STEP)                                                    \
    {                                                                           \
        const float* qp = &Q[(i0 + (size_t)(STEP) * 32 + kp * 2) * 2048         \
                             + n0 + nq * 4];                                    \
        AQ = *(const float4*)qp;                                                \
        AR = *(const float4*)(qp + 2048);                                       \
    }

#define WRITE_A(AQ, AR, STEP)                                                   \
    {                                                                           \
        const float* ca = (const float*)&AQ;                                    \
        const float* cb = (const float*)&AR;                                    \
        ushort4 s0, s1;                                                         \
        u16* q0 = (u16*)&s0; u16* q1 = (u16*)&s1;                               \
        _Pragma("unroll")                                                       \
        for (int jj = 0; jj < 4; ++jj) {                                        \
            const int n_ = nq * 4 + jj;                                         \
            ushort2 p2;                                                         \
            p2.x = f2bf(ca[jj]); p2.y = f2bf(cb[jj]);                           \
            *(ushort2*)&At[n_ * 34 + ((n_ & 1) << 1) + kp * 2] = p2;            \
            csum[jj] += ca[jj] + cb[jj];                                        \
            q0[jj] = p2.x; q1[jj] = p2.y;                                       \
        }                                                                       \
        const size_t r0 = i0 + (size_t)(STEP) * 32 + kp * 2;                    \
        *(ushort4*)&Qbf[r0 * 2048 + n0 + nq * 4] = s0;                          \
        *(ushort4*)&Qbf[(r0 + 1) * 2048 + n0 + nq * 4] = s1;                    \
    }

#define MFMA_PHASE(PAR)                                                         \
    {                                                                           \
        const u16* Bb = Bt[PAR];                                                \
        const int g = l >> 4;                                                   \
        FragA af[4];                                                            \
        _Pragma("unroll")                                                       \
        for (int nt = 0; nt < 4; ++nt) {                                        \
            const int r = nt * 16 + (l & 15);                                   \
            const int ab = r * 34 + ((r & 1) << 1) + g * 8;                     \
            af[nt].u2[0] = *(const uint2*)&At[ab];                              \
            af[nt].u2[1] = *(const uint2*)&At[ab + 4];                          \
        }                                                                       \
        _Pragma("unroll")                                                       \
        for (int c = 0; c < 4; ++c) {                                           \
            if (c < nct) {                                                      \
                const int rb = (ct0 + c) * 16 + (l & 15);                       \
                Frag bf;                                                        \
                bf.v = *(const short8*)&Bb[rb * 32 + ((g ^ ((rb >> 1) & 3)) << 3)]; \
                _Pragma("unroll")                                               \
                for (int nt = 0; nt < 4; ++nt)                                  \
                    acc[nt][c] = __builtin_amdgcn_mfma_f32_16x16x32_bf16(       \
                        af[nt].v, bf.v, acc[nt][c], 0, 0, 0);                   \
            }                                                                   \
        }                                                                       \
    }

#define STEPBODY(STEP, PAR, NPAR, CQ, CR, NQr, NRr, COND)                       \
    {                                                                           \
        if (COND) ISSUE_B(NPAR, (STEP) + 1);                                    \
        WRITE_A(CQ, CR, STEP);                                                  \
        if (COND) LOAD_A(NQr, NRr, (STEP) + 1);                                 \
        asm volatile("s_waitcnt lgkmcnt(0)" ::: "memory");                      \
        __builtin_amdgcn_s_barrier();                                           \
        if (COND) {                                                             \
            if (w == 0) asm volatile("s_waitcnt vmcnt(8)" ::: "memory");        \
            else        asm volatile("s_waitcnt vmcnt(7)" ::: "memory");        \
        } else {                                                                \
            asm volatile("s_waitcnt vmcnt(0)" ::: "memory");                    \
        }                                                                       \
        MFMA_PHASE(PAR);                                                        \
        __builtin_amdgcn_s_barrier();                                           \
    }

    ISSUE_B(0, 0);
    LOAD_A(aq0, ar0, 0);

    for (int s2 = 0; s2 < 32; ++s2) {
        STEPBODY(s2 * 2,     0, 1, aq0, ar0, aq1, ar1, true);
        STEPBODY(s2 * 2 + 1, 1, 0, aq1, ar1, aq0, ar0, (s2 < 31));
    }
#undef STEPBODY
#undef MFMA_PHASE
#undef WRITE_A
#undef LOAD_A
#undef ISSUE_B

    // ---- colsum reduce (reuse At as float scratch: 16x64 = 4KB) ----
    __syncthreads();
    float* csF = (float*)At;
#pragma unroll
    for (int jj = 0; jj < 4; ++jj)
        csF[kp * 64 + nq * 4 + jj] = csum[jj];
    __syncthreads();
    if (t < 64) {
        float s = 0.f;
#pragma unroll
        for (int g2 = 0; g2 < 16; ++g2) s += csF[g2 * 64 + t];
        csPart[(size_t)ks_b * 2048 + n0 + t] = s;
    }
    // ---- S partial stores (non-atomic) ----
    float* Sp = S_part + (size_t)ks_b * 409600;
#pragma unroll
    for (int nt = 0; nt < 4; ++nt)
#pragma unroll
        for (int c = 0; c < 4; ++c) {
            if (c < nct) {
                const int cc = (ct0 + c) * 16 + (l & 15);
                if (cc < 200) {
                    const int nbase = n0 + nt * 16 + ((l >> 4) << 2);
#pragma unroll
                    for (int r = 0; r < 4; ++r)
                        Sp[(size_t)(nbase + r) * 200 + cc] = acc[nt][c][r];
                }
            }
        }
}

// xn = BN * (sum_ks S_part) / (sum_ks csPart) ; xg = BN * xn  (csum merged)
__global__ void k_redS(const float* __restrict__ S_part, const float* __restrict__ csPart,
                       float* __restrict__ xn, float* __restrict__ xg) {
    int i = blockIdx.x * 256 + threadIdx.x;
    if (i >= N * C) return;
    int n = i / C;
    float s = 0.f, csn = 0.f;
#pragma unroll 8
    for (int p = 0; p < 32; ++p) s += S_part[(size_t)p * 409600 + i];
#pragma unroll 8
    for (int p = 0; p < 32; ++p) csn += csPart[(size_t)p * 2048 + n];
    float v = BNF * s / csn;
    xn[i] = v;
    xg[i] = BNF * v;
}

// CSR build
__global__ void k_csr(const float* __restrict__ adj, int* __restrict__ deg,
                      int* __restrict__ idxs) {
    int w = threadIdx.x >> 6, lane = threadIdx.x & 63;
    int n = blockIdx.x * 4 + w;
    const float* row = adj + (size_t)n * N;
    int base = 0;
    for (int c = 0; c < N; c += 64) {
        float v = row[c + lane];
        bool p = v > 0.f;
        unsigned long long m = __ballot(p);
        int pos = __popcll(m & ((1ull << lane) - 1ull));
        if (p && (base + pos) < MAXDEG) idxs[(size_t)n * MAXDEG + base + pos] = c + lane;
        base += __popcll(m);
    }
    if (lane == 0) deg[n] = base < MAXDEG ? base : MAXDEG;
}

// generic small dense mm (GCN branch)
__global__ __launch_bounds__(256) void k_mm(const float* __restrict__ A,
                                            const float* __restrict__ W,
                                            float* __restrict__ Cc,
                                            int K, int Wout, int ostride,
                                            int zc_off, int zw_str, float scale) {
    __shared__ float ldsA[32][33];
    __shared__ float ldsW[32][64];
    const int rt = blockIdx.x * 32;
    const int ct = blockIdx.y * 64;
    const int z  = blockIdx.z;
    const float* Wp = W + (size_t)z * zw_str;
    const int coff = z * zc_off;
    const int t = threadIdx.x;
    const int lane = t & 63, wg = t >> 6;
    float acc[8];
#pragma unroll
    for (int r = 0; r < 8; ++r) acc[r] = 0.f;

    for (int k0 = 0; k0 < K; k0 += 32) {
        for (int idx = t; idx < 32 * 32; idx += 256) {
            int r = idx >> 5, kk = idx & 31;
            int k = k0 + kk;
            ldsA[r][kk] = (k < K) ? A[(size_t)(rt + r) * K + k] : 0.f;
        }
        for (int idx = t; idx < 32 * 64; idx += 256) {
            int kk = idx >> 6, c = idx & 63;
            int k = k0 + kk, cg = ct + c;
            ldsW[kk][c] = (k < K && cg < Wout) ? Wp[(size_t)k * Wout + cg] : 0.f;
        }
        __syncthreads();
#pragma unroll 8
        for (int kk = 0; kk < 32; ++kk) {
            float wv = ldsW[kk][lane];
#pragma unroll
            for (int r = 0; r < 8; ++r) acc[r] += ldsA[wg * 8 + r][kk] * wv;
        }
        __syncthreads();
    }
    int cg = ct + lane;
    if (cg < Wout) {
#pragma unroll
        for (int r = 0; r < 8; ++r)
            Cc[(size_t)(rt + wg * 8 + r) * ostride + coff + cg] = scale * acc[r];
    }
}

// out[n,k] = (res?res:0) + act( s*(sum_nbr h + bias) )
__global__ void k_spmm(const float* __restrict__ h, const int* __restrict__ deg,
                       const int* __restrict__ idxs, const float* __restrict__ bias,
                       const float* __restrict__ res, float* __restrict__ out,
                       int W, float s, int act) {
    int n = blockIdx.x;
    int d = deg[n];
    const int* row = idxs + (size_t)n * MAXDEG;
    int k0 = threadIdx.x;
    int k1 = threadIdx.x + 128;
    float a0 = 0.f, a1 = 0.f;
    for (int j = 0; j < d; ++j) {
        const float* hr = h + (size_t)row[j] * W;
        a0 += hr[k0];
        if (k1 < W) a1 += hr[k1];
    }
    {
        float v = s * (a0 + bias[k0]);
        if (act) v = v >= 0.f ? v : 0.01f * v;
        if (res) v += res[(size_t)n * W + k0];
        out[(size_t)n * W + k0] = v;
    }
    if (k1 < W) {
        float v = s * (a1 + bias[k1]);
        if (act) v = v >= 0.f ? v : 0.01f * v;
        if (res) v += res[(size_t)n * W + k1];
        out[(size_t)n * W + k1] = v;
    }
}

// ---------------------------------------------------------------------------
// Merged: z<4 -> GAT Wh head z (+f1/f2 epilogue); z==4 -> GCN mm1 (BNF^2).
// All are [2048x200]@[200x128]; grid (64, 5), block 256.
// ---------------------------------------------------------------------------
__global__ __launch_bounds__(256) void k_wh5(const float* __restrict__ xn,
                                             const float* __restrict__ gatW,
                                             const float* __restrict__ gata,
                                             const float* __restrict__ g1aW,
                                             float* __restrict__ WhB,
                                             float* __restrict__ f1,
                                             float* __restrict__ f2,
                                             float* __restrict__ hbuf) {
    __shared__ float ldsA[32][33];
    __shared__ float ldsW[32][128];
    __shared__ float ldsWh[32][129];
    const int rt = blockIdx.x * 32;
    const int z  = blockIdx.y;
    const bool gat = z < 4;
    const float* Wp = gat ? gatW + (size_t)z * 25600 : g1aW;
    const int t = threadIdx.x;
    const int col = t & 127, rg = t >> 7;
    float acc[16];
#pragma unroll
    for (int r = 0; r < 16; ++r) acc[r] = 0.f;

    for (int k0 = 0; k0 < 200; k0 += 32) {
        for (int idx = t; idx < 32 * 32; idx += 256) {
            int r = idx >> 5, kk = idx & 31;
            int k = k0 + kk;
            ldsA[r][kk] = (k < 200) ? xn[(size_t)(rt + r) * 200 + k] : 0.f;
        }
        for (int idx = t; idx < 32 * 128; idx += 256) {
            int kk = idx >> 7, c = idx & 127;
            int k = k0 + kk;
            ldsW[kk][c] = (k < 200) ? Wp[(size_t)k * 128 + c] : 0.f;
        }
        __syncthreads();
#pragma unroll 8
        for (int kk = 0; kk < 32; ++kk) {
            float wv = ldsW[kk][col];
#pragma unroll
            for (int r = 0; r < 16; ++r) acc[r] += ldsA[rg * 16 + r][kk] * wv;
        }
        __syncthreads();
    }
    if (gat) {
#pragma unroll
        for (int r = 0; r < 16; ++r) {
            ldsWh[rg * 16 + r][col] = acc[r];
            WhB[(size_t)(rt + rg * 16 + r) * 512 + z * 128 + col] = acc[r];
        }
        __syncthreads();
        int row = t >> 3, p = t & 7;
        const float* a = gata + z * 256;
        float s1 = 0.f, s2 = 0.f;
#pragma unroll
        for (int j = 0; j < 16; ++j) {
            int c = p * 16 + j;
            float v = ldsWh[row][c];
            s1 += v * a[c]; s2 += v * a[128 + c];
        }
        s1 += __shfl_xor(s1, 1); s1 += __shfl_xor(s1, 2); s1 += __shfl_xor(s1, 4);
        s2 += __shfl_xor(s2, 1); s2 += __shfl_xor(s2, 2); s2 += __shfl_xor(s2, 4);
        if (p == 0) { f1[z * N + rt + row] = s1; f2[z * N + rt + row] = s2; }
    } else {
        const float sc = BNF * BNF;
#pragma unroll
        for (int r = 0; r < 16; ++r)
            hbuf[(size_t)(rt + rg * 16 + r) * 128 + col] = sc * acc[r];
    }
}

// per-head attention: e-weights staged in LDS, single WhB gather pass
__global__ void k_att_head(const float* __restrict__ WhB, const float* __restrict__ f1,
                           const float* __restrict__ f2, const int* __restrict__ deg,
                           const int* __restrict__ idxs, float* __restrict__ hcat) {
    __shared__ float eW[MAXDEG];
    int n = blockIdx.x, h = blockIdx.y;
    int k = threadIdx.x;          // 128
    int d = deg[n];
    const int* row = idxs + (size_t)n * MAXDEG;
    float f1v = f1[h * N + n];
    const float* f2h = f2 + h * N;
    if (k < d) {
        float e = f1v + f2h[row[k]];
        eW[k] = e >= 0.f ? e : 0.2f * e;
    }
    __syncthreads();
    float mx = -1e30f;
    for (int j = 0; j < d; ++j) mx = fmaxf(mx, eW[j]);
    __syncthreads();
    if (k < d) eW[k] = __expf(eW[k] - mx);
    __syncthreads();
    float ssum = 0.f, acc = 0.f;
    for (int j = 0; j < d; ++j) ssum += eW[j];
    for (int j = 0; j < d; ++j)
        acc += eW[j] * WhB[(size_t)row[j] * 512 + h * 128 + k];
    float v = acc / ssum;
    v = v > 0.f ? v : __expf(v) - 1.f;
    hcat[(size_t)n * 512 + h * 128 + k] = v;
}

// WhO = hcat @ outW (32x64, K=512) + f1o/f2o row-dot epilogue
__global__ __launch_bounds__(256) void k_mmO(const float* __restrict__ hcat,
                                             const float* __restrict__ outW,
                                             const float* __restrict__ outa,
                                             float* __restrict__ WhO,
                                             float* __restrict__ f1o,
                                             float* __restrict__ f2o) {
    __shared__ float ldsA[32][33];
    __shared__ float ldsW[32][64];
    const int rt = blockIdx.x * 32;
    const int t = threadIdx.x;
    const int lane = t & 63, wg = t >> 6;
    float acc[8];
#pragma unroll
    for (int r = 0; r < 8; ++r) acc[r] = 0.f;

    for (int k0 = 0; k0 < 512; k0 += 32) {
        for (int idx = t; idx < 32 * 32; idx += 256) {
            int r = idx >> 5, kk = idx & 31;
            ldsA[r][kk] = hcat[(size_t)(rt + r) * 512 + k0 + kk];
        }
        for (int idx = t; idx < 32 * 64; idx += 256) {
            int kk = idx >> 6, c = idx & 63;
            ldsW[kk][c] = outW[(size_t)(k0 + kk) * 64 + c];
        }
        __syncthreads();
#pragma unroll 8
        for (int kk = 0; kk < 32; ++kk) {
            float wv = ldsW[kk][lane];
#pragma unroll
            for (int r = 0; r < 8; ++r) acc[r] += ldsA[wg * 8 + r][kk] * wv;
        }
        __syncthreads();
    }
#pragma unroll
    for (int r = 0; r < 8; ++r)
        WhO[(size_t)(rt + wg * 8 + r) * 64 + lane] = acc[r];
#pragma unroll
    for (int r = 0; r < 8; ++r) {
        float v1 = acc[r] * outa[lane];
        float v2 = acc[r] * outa[64 + lane];
#pragma unroll
        for (int off = 32; off; off >>= 1) {
            v1 += __shfl_down(v1, off);
            v2 += __shfl_down(v2, off);
        }
        if (lane == 0) { f1o[rt + wg * 8 + r] = v1; f2o[rt + wg * 8 + r] = v2; }
    }
}

// output attention (LDS-weights single gather) + elu + bn + lrelu + fusion
// + conv + bn + lrelu -> yT [64][2048] bf16
__global__ void k_att_out(const float* __restrict__ WhO, const float* __restrict__ f1o,
                          const float* __restrict__ f2o, const int* __restrict__ deg,
                          const int* __restrict__ idxs, const float* __restrict__ GCNx,
                          const float* __restrict__ Wf, const float* __restrict__ bfp,
                          const float* __restrict__ cw, const float* __restrict__ cb,
                          u16* __restrict__ yT) {
    __shared__ float eW[MAXDEG];
    int n = blockIdx.x;
    int k = threadIdx.x;   // 64
    int d = deg[n];
    const int* row = idxs + (size_t)n * MAXDEG;
    float f1v = f1o[n];
    for (int j = k; j < d; j += 64) {
        float e = f1v + f2o[row[j]];
        eW[j] = e >= 0.f ? e : 0.2f * e;
    }
    __syncthreads();
    float mx = -1e30f;
    for (int j = 0; j < d; ++j) mx = fmaxf(mx, eW[j]);
    __syncthreads();
    for (int j = k; j < d; j += 64) eW[j] = __expf(eW[j] - mx);
    __syncthreads();
    float ssum = 0.f, acc = 0.f;
    for (int j = 0; j < d; ++j) ssum += eW[j];
    for (int j = 0; j < d; ++j)
        acc += eW[j] * WhO[(size_t)row[j] * 64 + k];
    float v = acc / ssum;
    v = v > 0.f ? v : __expf(v) - 1.f;   // elu
    v *= BNF;
    float gat = v >= 0.f ? v : 0.01f * v;
    float g = GCNx[(size_t)n * 64 + k];
    float mn = fminf(g, gat), mxv = fmaxf(g, gat);
    float avg = g * Wf[k] + bfp[k] + gat * Wf[64 + k] + bfp[64 + k];
    float base = g + gat;
    float yv = cw[0] * (mn + base) + cw[1] * (mxv + base) + cw[2] * (avg + base) + cb[0];
    yv *= BNF;
    yv = yv >= 0.f ? yv : 0.2f * yv;
    yT[k * 2048 + n] = f2bf(yv);
}

// ---------------------------------------------------------------------------
// out[i,f] = sum_n Qbf[i,n]*yT[f,n]. Tile 128i x 64f, K-step 64, dbuf LDS,
// counted vmcnt, grid 512, 3 blocks/CU, direct stores.
// ---------------------------------------------------------------------------
__global__ __launch_bounds__(256, 3) void k_final(const u16* __restrict__ Qbf,
                                                  const u16* __restrict__ yT,
                                                  float* __restrict__ out) {
    __shared__ __align__(16) u16 Aq[2][128 * 64];
    __shared__ __align__(16) u16 By[2][64 * 64];
    const int i0 = blockIdx.x * 128;
    const int t = threadIdx.x, w = t >> 6, l = t & 63;
    const int lrow = l >> 3;
    const int scol = (((l & 7) ^ ((l >> 3) & 7)) << 3);
    f32x4 acc[2][4];
#pragma unroll
    for (int a = 0; a < 2; ++a)
#pragma unroll
        for (int b = 0; b < 4; ++b) acc[a][b] = (f32x4){0.f, 0.f, 0.f, 0.f};

#define STAGE_F(buf, step)                                                          \
    {                                                                               \
        const size_t kc = (size_t)(step) * 64 + scol;                               \
        for (int s = w; s < 16; s += 4)                                             \
            gload16(&Qbf[(size_t)(i0 + s * 8 + lrow) * 2048 + kc],                  \
                    &Aq[buf][s * 512]);                                             \
        for (int s = w; s < 8; s += 4)                                              \
            gload16(&yT[(size_t)(s * 8 + lrow) * 2048 + kc],                        \
                    &By[buf][s * 512]);                                             \
    }

    STAGE_F(0, 0);
    for (int step = 0; step < 32; ++step) {
        const int cur = step & 1;
        if (step + 1 < 32) {
            STAGE_F(cur ^ 1, step + 1);
            asm volatile("s_waitcnt vmcnt(6)" ::: "memory");
        } else {
            asm volatile("s_waitcnt vmcnt(0)" ::: "memory");
        }
        __builtin_amdgcn_s_barrier();

        const u16* Ab = Aq[cur];
        const u16* Bb = By[cur];
#pragma unroll
        for (int sub = 0; sub < 2; ++sub) {
            const int c8 = sub * 4 + (l >> 4);
            Frag a[2];
#pragma unroll
            for (int it = 0; it < 2; ++it) {
                const int r = w * 32 + it * 16 + (l & 15);
                a[it].v = *(const short8*)&Ab[r * 64 + ((c8 ^ (r & 7)) << 3)];
            }
#pragma unroll
            for (int ft = 0; ft < 4; ++ft) {
                const int rb = ft * 16 + (l & 15);
                Frag b;
                b.v = *(const short8*)&Bb[rb * 64 + ((c8 ^ (rb & 7)) << 3)];
#pragma unroll
                for (int it = 0; it < 2; ++it)
                    acc[it][ft] = __builtin_amdgcn_mfma_f32_16x16x32_bf16(
                        a[it].v, b.v, acc[it][ft], 0, 0, 0);
            }
        }
        asm volatile("s_waitcnt lgkmcnt(0)" ::: "memory");
        __builtin_amdgcn_s_barrier();
    }
#undef STAGE_F
#pragma unroll
    for (int it = 0; it < 2; ++it)
#pragma unroll
        for (int ft = 0; ft < 4; ++ft) {
            const int i = i0 + w * 32 + it * 16 + ((l >> 4) << 2);
            const int f = ft * 16 + (l & 15);
#pragma unroll
            for (int r = 0; r < 4; ++r)
                out[(size_t)(i + r) * 64 + f] = acc[it][ft][r];
        }
}

extern "C" void kernel_launch(void* const* d_in, const int* in_sizes, int n_in,
                              void* d_out, int out_size, void* d_ws, size_t ws_size,
                              hipStream_t stream) {
    const float* x     = (const float*)d_in[0];
    const float* adj   = (const float*)d_in[1];
    const float* Q     = (const float*)d_in[2];
    const float* g1aW  = (const float*)d_in[3];
    const float* g1ab  = (const float*)d_in[4];
    const float* g1bW  = (const float*)d_in[5];
    const float* g1bb  = (const float*)d_in[6];
    const float* g2aW  = (const float*)d_in[7];
    const float* g2ab  = (const float*)d_in[8];
    const float* g2bW  = (const float*)d_in[9];
    const float* g2bb  = (const float*)d_in[10];
    const float* gatW  = (const float*)d_in[11];
    const float* gata  = (const float*)d_in[12];
    const float* outW  = (const float*)d_in[13];
    const float* outa  = (const float*)d_in[14];
    const float* Wf    = (const float*)d_in[15];
    const float* bfp   = (const float*)d_in[16];
    const float* convw = (const float*)d_in[17];
    const float* convb = (const float*)d_in[18];

    float* ws   = (float*)d_ws;
    float* xn   = ws + 411648;
    float* xg   = ws + 821248;
    float* xg2  = ws + 1230848;
    float* hbuf = ws + 1640448;
    float* zbuf = ws + 2050048;
    float* WhO  = ws + 2312192;
    float* GCNx = ws + 2443264;
    float* f1   = ws + 2836480;
    float* f2   = ws + 2844672;
    float* f1o  = ws + 2852864;
    float* f2o  = ws + 2854912;
    int*   deg  = (int*)(ws + 2856960);
    int*   idxs = (int*)(ws + 2859008);
    u16*   yT   = (u16*)(ws + 1640448);           // reuses hbuf region
    float* csPart = ws + 3000000;                 // 32*2048 f32
    float* S_part = ws + 4200000;                 // 32*409600 f32 = 52 MB
    u16*   Qbf    = (u16*)(ws + 71308864);        // 65536*2048 u16 = 256MB
    u16*   xfT    = (u16*)(ws + 138417728);       // 208*65536 u16

    float* out  = (float*)d_out;
    float* WhB  = out;             // 2048*512 scratch inside d_out
    float* hcat = out + 1048576;   // 2048*512 scratch inside d_out

    // ---- conversion + big S GEMM (fused: Q read once in f32) ----
    k_convX<<<512, 256, 0, stream>>>(x, xfT);
    k_bigS<<<1024, 256, 0, stream>>>(Q, xfT, Qbf, S_part, csPart);
    k_redS<<<(N * C + 255) / 256, 256, 0, stream>>>(S_part, csPart, xn, xg);
    k_csr<<<N / 4, 256, 0, stream>>>(adj, deg, idxs);

    // ---- merged first GEMMs: GAT Wh (4 heads) + GCN mm1 ----
    k_wh5<<<dim3(64, 5), 256, 0, stream>>>(xn, gatW, gata, g1aW, WhB, f1, f2, hbuf);

    // ---- GCN + GAT chains ----
    k_spmm<<<N, 128, 0, stream>>>(hbuf, deg, idxs, g1ab, nullptr, zbuf, 128, 1.f, 1);
    k_att_head<<<dim3(N, 4), 128, 0, stream>>>(WhB, f1, f2, deg, idxs, hcat);
    k_mm<<<dim3(64, 4, 1), 256, 0, stream>>>(zbuf, g1bW, hbuf, 128, 200, 200, 0, 0, BNF);
    k_mmO<<<64, 256, 0, stream>>>(hcat, outW, outa, WhO, f1o, f2o);
    k_spmm<<<N, 128, 0, stream>>>(hbuf, deg, idxs, g1bb, xg, xg2, 200, BNF, 1);
    k_mm<<<dim3(64, 2, 1), 256, 0, stream>>>(xg2, g2aW, hbuf, 200, 128, 128, 0, 0, BNF);
    k_spmm<<<N, 128, 0, stream>>>(hbuf, deg, idxs, g2ab, nullptr, zbuf, 128, 1.f, 1);
    k_mm<<<dim3(64, 1, 1), 256, 0, stream>>>(zbuf, g2bW, hbuf, 128, 64, 64, 0, 0, BNF);
    k_spmm<<<N, 64, 0, stream>>>(hbuf, deg, idxs, g2bb, nullptr, GCNx, 64, BNF, 1);

    // ---- output attention + fusion -> yT ----
    k_att_out<<<N, 64, 0, stream>>>(WhO, f1o, f2o, deg, idxs, GCNx,
                                    Wf, bfp, convw, convb, yT);

    // ---- final projection (overwrites WhB/hcat scratch in d_out) ----
    k_final<<<512, 256, 0, stream>>>(Qbf, yT, out);
}

// Round 10
// 694.479 us; speedup vs baseline: 1.3568x; 1.0433x over previous
//
#include <hip/hip_runtime.h>
#include <math.h>

#define BNF 0.9999950000374997f

constexpr int N    = 2048;
constexpr int C    = 200;
constexpr int HW   = 65536;
constexpr int MAXDEG = 96;

typedef unsigned short u16;
typedef __attribute__((ext_vector_type(8))) short short8;
typedef __attribute__((ext_vector_type(4))) float f32x4;

union Frag  { short8 v; ushort4 h[2]; };
union FragA { short8 v; uint2 u2[2]; };

__device__ inline u16 f2bf(float x) {
    unsigned int u = __float_as_uint(x);
    unsigned int r = (u + 0x7fffu + ((u >> 16) & 1u)) >> 16;
    return (u16)r;
}

// async global->LDS, 16B per lane, wave-uniform LDS base, per-lane global addr
__device__ __forceinline__ void gload16(const void* g, void* l) {
    __builtin_amdgcn_global_load_lds(
        (const __attribute__((address_space(1))) unsigned int*)g,
        (__attribute__((address_space(3))) unsigned int*)l, 16, 0, 0);
}

// ---------------------------------------------------------------------------
// xf [65536][200] f32 -> xfT [208][65536] bf16 (rows 200..207 zeroed)
// ---------------------------------------------------------------------------
__global__ __launch_bounds__(256) void k_convX(const float* __restrict__ xf,
                                               u16* __restrict__ xfT) {
    __shared__ __align__(16) u16 T2[200][140];
    const int i0 = blockIdx.x * 128;
    const int t = threadIdx.x;
    for (int p = 0; p < 25; ++p) {
        int idx = p * 256 + t;
        int il = idx / 50, cq = idx % 50;
        float4 v = *(const float4*)&xf[(size_t)(i0 + il) * 200 + cq * 4];
        T2[cq * 4 + 0][il] = f2bf(v.x);
        T2[cq * 4 + 1][il] = f2bf(v.y);
        T2[cq * 4 + 2][il] = f2bf(v.z);
        T2[cq * 4 + 3][il] = f2bf(v.w);
    }
    __syncthreads();
    for (int p = 0; p < 13; ++p) {
        int c = p * 16 + (t >> 4);
        if (c < 200) {
            int io = (t & 15) * 8;
            u16* dst = &xfT[(size_t)c * 65536 + i0 + io];
            *(ushort4*)&dst[0] = *(const ushort4*)&T2[c][io];
            *(ushort4*)&dst[4] = *(const ushort4*)&T2[c][io + 4];
        }
    }
    ushort4 z4 = {0, 0, 0, 0};
    for (int idx = t; idx < 8 * 16; idx += 256) {
        int r = 200 + (idx >> 4), io = (idx & 15) * 8;
        u16* dst = &xfT[(size_t)r * 65536 + i0 + io];
        *(ushort4*)&dst[0] = z4;
        *(ushort4*)&dst[4] = z4;
    }
}

// ---------------------------------------------------------------------------
// Fused conversion + S-partial GEMM, 64n x 208c tile, 3 blocks/CU.
// Dist-2 Q prefetch; corrected counted vmcnt(12/11) (T4 formula).
// grid 1024 flat (32 nt x 32 ks, XCD remap), block 256 (4 waves), K-step 32.
// ---------------------------------------------------------------------------
__global__ __launch_bounds__(256, 3) void k_bigS(const float* __restrict__ Q,
                                                 const u16* __restrict__ xfT,
                                                 u16* __restrict__ Qbf,
                                                 float* __restrict__ S_part,
                                                 float* __restrict__ csPart) {
    __shared__ __align__(16) u16 Bt[2][208 * 32];   // 13 KB per buf
    __shared__ __align__(16) u16 At[64 * 34];       // 4.3 KB
    const int bid = blockIdx.x;
    const int xcd = bid & 7, jb = bid >> 3;
    const int nt_b = jb & 31;
    const int ks_b = ((jb >> 5) << 3) + xcd;        // same-slab blocks -> same XCD
    const int n0 = nt_b * 64;
    const size_t i0 = (size_t)ks_b * 2048;
    const int t = threadIdx.x, w = t >> 6, l = t & 63;
    const int ct0 = (w == 0) ? 0 : (4 + (w - 1) * 3);
    const int nct = (w == 0) ? 4 : 3;
    const int lrowB = l >> 2;
    const int scolB = (((l & 3) ^ ((l >> 3) & 3)) << 3);
    const int nq = t & 15;
    const int kp = t >> 4;

    f32x4 acc[4][4];
#pragma unroll
    for (int a = 0; a < 4; ++a)
#pragma unroll
        for (int b = 0; b < 4; ++b) acc[a][b] = (f32x4){0.f, 0.f, 0.f, 0.f};
    float csum[4] = {0.f, 0.f, 0.f, 0.f};

    float4 aq0, ar0, aq1, ar1;

#define ISSUE_B(PAR, STEP)                                                      \
    {                                                                           \
        const size_t kc = i0 + (size_t)(STEP) * 32 + scolB;                     \
        for (int s = w; s < 13; s += 4)                                         \
            gload16(&xfT[(size_t)(s * 16 + lrowB) * 65536 + kc],                \
                    &Bt[PAR][s * 512]);                                         \
    }

#define LOAD_A(AQ, AR, STEP)                                                    \
    {                                                                           \
        const float* qp = &Q[(i0 + (size_t)(STEP) * 32 + kp * 2) * 2048         \
                             + n0 + nq * 4];                                    \
        AQ = *(const float4*)qp;                                                \
        AR = *(const float4*)(qp + 2048);                                       \
    }

#define WRITE_A(AQ, AR, STEP)                                                   \
    {                                                                           \
        const float* ca = (const float*)&AQ;                                    \
        const float* cb = (const float*)&AR;                                    \
        ushort4 s0, s1;                                                         \
        u16* q0 = (u16*)&s0; u16* q1 = (u16*)&s1;                               \
        _Pragma("unroll")                                                       \
        for (int jj = 0; jj < 4; ++jj) {                                        \
            const int n_ = nq * 4 + jj;                                         \
            ushort2 p2;                                                         \
            p2.x = f2bf(ca[jj]); p2.y = f2bf(cb[jj]);                           \
            *(ushort2*)&At[n_ * 34 + ((n_ & 1) << 1) + kp * 2] = p2;            \
            csum[jj] += ca[jj] + cb[jj];                                        \
            q0[jj] = p2.x; q1[jj] = p2.y;                                       \
        }                                                                       \
        const size_t r0 = i0 + (size_t)(STEP) * 32 + kp * 2;                    \
        *(ushort4*)&Qbf[r0 * 2048 + n0 + nq * 4] = s0;                          \
        *(ushort4*)&Qbf[(r0 + 1) * 2048 + n0 + nq * 4] = s1;                    \
    }

#define MFMA_PHASE(PAR)                                                         \
    {                                                                           \
        const u16* Bb = Bt[PAR];                                                \
        const int g = l >> 4;                                                   \
        FragA af[4];                                                            \
        _Pragma("unroll")                                                       \
        for (int nt = 0; nt < 4; ++nt) {                                        \
            const int r = nt * 16 + (l & 15);                                   \
            const int ab = r * 34 + ((r & 1) << 1) + g * 8;                     \
            af[nt].u2[0] = *(const uint2*)&At[ab];                              \
            af[nt].u2[1] = *(const uint2*)&At[ab + 4];                          \
        }                                                                       \
        _Pragma("unroll")                                                       \
        for (int c = 0; c < 4; ++c) {                                           \
            if (c < nct) {                                                      \
                const int rb = (ct0 + c) * 16 + (l & 15);                       \
                Frag bf;                                                        \
                bf.v = *(const short8*)&Bb[rb * 32 + ((g ^ ((rb >> 1) & 3)) << 3)]; \
                _Pragma("unroll")                                               \
                for (int nt = 0; nt < 4; ++nt)                                  \
                    acc[nt][c] = __builtin_amdgcn_mfma_f32_16x16x32_bf16(       \
                        af[nt].v, bf.v, acc[nt][c], 0, 0, 0);                   \
            }                                                                   \
        }                                                                       \
    }

// Per step (w0) issues: B x4 (next), store x2, load x2 = 8 VMEM ops.
// Current-step B was issued last step; ops after it = 4 (tail of last step)
// + 8 (this step) = 12 -> vmcnt(12); w>=1 issue 3 B -> 11.  Dummy tail loads
// (clamped step) keep counts uniform & safe.
#define STEPBODY(STEP, PAR, NPAR, CQ, CR, COND)                                 \
    {                                                                           \
        if (COND) ISSUE_B(NPAR, (STEP) + 1);                                    \
        WRITE_A(CQ, CR, STEP);                                                  \
        {                                                                       \
            const int nst = ((STEP) + 2 > 63) ? 63 : (STEP) + 2;                \
            LOAD_A(CQ, CR, nst);                                                \
        }                                                                       \
        asm volatile("s_waitcnt lgkmcnt(0)" ::: "memory");                      \
        __builtin_amdgcn_s_barrier();                                           \
        if (COND) {                                                             \
            if (w == 0) asm volatile("s_waitcnt vmcnt(12)" ::: "memory");       \
            else        asm volatile("s_waitcnt vmcnt(11)" ::: "memory");       \
        } else {                                                                \
            asm volatile("s_waitcnt vmcnt(0)" ::: "memory");                    \
        }                                                                       \
        MFMA_PHASE(PAR);                                                        \
        __builtin_amdgcn_s_barrier();                                           \
    }

    ISSUE_B(0, 0);
    LOAD_A(aq0, ar0, 0);
    LOAD_A(aq1, ar1, 1);

    for (int s2 = 0; s2 < 32; ++s2) {
        STEPBODY(s2 * 2,     0, 1, aq0, ar0, true);
        STEPBODY(s2 * 2 + 1, 1, 0, aq1, ar1, (s2 < 31));
    }
#undef STEPBODY
#undef MFMA_PHASE
#undef WRITE_A
#undef LOAD_A
#undef ISSUE_B

    // ---- colsum reduce (reuse At as float scratch: 16x64 = 4KB) ----
    __syncthreads();
    float* csF = (float*)At;
#pragma unroll
    for (int jj = 0; jj < 4; ++jj)
        csF[kp * 64 + nq * 4 + jj] = csum[jj];
    __syncthreads();
    if (t < 64) {
        float s = 0.f;
#pragma unroll
        for (int g2 = 0; g2 < 16; ++g2) s += csF[g2 * 64 + t];
        csPart[(size_t)ks_b * 2048 + n0 + t] = s;
    }
    // ---- S partial stores (non-atomic) ----
    float* Sp = S_part + (size_t)ks_b * 409600;
#pragma unroll
    for (int nt = 0; nt < 4; ++nt)
#pragma unroll
        for (int c = 0; c < 4; ++c) {
            if (c < nct) {
                const int cc = (ct0 + c) * 16 + (l & 15);
                if (cc < 200) {
                    const int nbase = n0 + nt * 16 + ((l >> 4) << 2);
#pragma unroll
                    for (int r = 0; r < 4; ++r)
                        Sp[(size_t)(nbase + r) * 200 + cc] = acc[nt][c][r];
                }
            }
        }
}

// merged: bid<1600 -> redS (xn/xg); else -> CSR build (deg/idxs)
__global__ void k_aux(const float* __restrict__ S_part, const float* __restrict__ csPart,
                      float* __restrict__ xn, float* __restrict__ xg,
                      const float* __restrict__ adj, int* __restrict__ deg,
                      int* __restrict__ idxs) {
    const int bid = blockIdx.x;
    if (bid < 1600) {
        int i = bid * 256 + threadIdx.x;
        if (i >= N * C) return;
        int n = i / C;
        float s = 0.f, csn = 0.f;
#pragma unroll 8
        for (int p = 0; p < 32; ++p) s += S_part[(size_t)p * 409600 + i];
#pragma unroll 8
        for (int p = 0; p < 32; ++p) csn += csPart[(size_t)p * 2048 + n];
        float v = BNF * s / csn;
        xn[i] = v;
        xg[i] = BNF * v;
    } else {
        int w = threadIdx.x >> 6, lane = threadIdx.x & 63;
        int n = (bid - 1600) * 4 + w;
        const float* row = adj + (size_t)n * N;
        int base = 0;
        for (int c = 0; c < N; c += 64) {
            float v = row[c + lane];
            bool p = v > 0.f;
            unsigned long long m = __ballot(p);
            int pos = __popcll(m & ((1ull << lane) - 1ull));
            if (p && (base + pos) < MAXDEG) idxs[(size_t)n * MAXDEG + base + pos] = c + lane;
            base += __popcll(m);
        }
        if (lane == 0) deg[n] = base < MAXDEG ? base : MAXDEG;
    }
}

// generic small dense mm (GCN branch)
__global__ __launch_bounds__(256) void k_mm(const float* __restrict__ A,
                                            const float* __restrict__ W,
                                            float* __restrict__ Cc,
                                            int K, int Wout, int ostride,
                                            int zc_off, int zw_str, float scale) {
    __shared__ float ldsA[32][33];
    __shared__ float ldsW[32][64];
    const int rt = blockIdx.x * 32;
    const int ct = blockIdx.y * 64;
    const int z  = blockIdx.z;
    const float* Wp = W + (size_t)z * zw_str;
    const int coff = z * zc_off;
    const int t = threadIdx.x;
    const int lane = t & 63, wg = t >> 6;
    float acc[8];
#pragma unroll
    for (int r = 0; r < 8; ++r) acc[r] = 0.f;

    for (int k0 = 0; k0 < K; k0 += 32) {
        for (int idx = t; idx < 32 * 32; idx += 256) {
            int r = idx >> 5, kk = idx & 31;
            int k = k0 + kk;
            ldsA[r][kk] = (k < K) ? A[(size_t)(rt + r) * K + k] : 0.f;
        }
        for (int idx = t; idx < 32 * 64; idx += 256) {
            int kk = idx >> 6, c = idx & 63;
            int k = k0 + kk, cg = ct + c;
            ldsW[kk][c] = (k < K && cg < Wout) ? Wp[(size_t)k * Wout + cg] : 0.f;
        }
        __syncthreads();
#pragma unroll 8
        for (int kk = 0; kk < 32; ++kk) {
            float wv = ldsW[kk][lane];
#pragma unroll
            for (int r = 0; r < 8; ++r) acc[r] += ldsA[wg * 8 + r][kk] * wv;
        }
        __syncthreads();
    }
    int cg = ct + lane;
    if (cg < Wout) {
#pragma unroll
        for (int r = 0; r < 8; ++r)
            Cc[(size_t)(rt + wg * 8 + r) * ostride + coff + cg] = scale * acc[r];
    }
}

// out[n,k] = (res?res:0) + act( s*(sum_nbr h + bias) )
__global__ void k_spmm(const float* __restrict__ h, const int* __restrict__ deg,
                       const int* __restrict__ idxs, const float* __restrict__ bias,
                       const float* __restrict__ res, float* __restrict__ out,
                       int W, float s, int act) {
    int n = blockIdx.x;
    int d = deg[n];
    const int* row = idxs + (size_t)n * MAXDEG;
    int k0 = threadIdx.x;
    int k1 = threadIdx.x + 128;
    float a0 = 0.f, a1 = 0.f;
    for (int j = 0; j < d; ++j) {
        const float* hr = h + (size_t)row[j] * W;
        a0 += hr[k0];
        if (k1 < W) a1 += hr[k1];
    }
    {
        float v = s * (a0 + bias[k0]);
        if (act) v = v >= 0.f ? v : 0.01f * v;
        if (res) v += res[(size_t)n * W + k0];
        out[(size_t)n * W + k0] = v;
    }
    if (k1 < W) {
        float v = s * (a1 + bias[k1]);
        if (act) v = v >= 0.f ? v : 0.01f * v;
        if (res) v += res[(size_t)n * W + k1];
        out[(size_t)n * W + k1] = v;
    }
}

// ---------------------------------------------------------------------------
// Merged: z<4 -> GAT Wh head z (+f1/f2 epilogue); z==4 -> GCN mm1 (BNF^2).
// ---------------------------------------------------------------------------
__global__ __launch_bounds__(256) void k_wh5(const float* __restrict__ xn,
                                             const float* __restrict__ gatW,
                                             const float* __restrict__ gata,
                                             const float* __restrict__ g1aW,
                                             float* __restrict__ WhB,
                                             float* __restrict__ f1,
                                             float* __restrict__ f2,
                                             float* __restrict__ hbuf) {
    __shared__ float ldsA[32][33];
    __shared__ float ldsW[32][128];
    __shared__ float ldsWh[32][129];
    const int rt = blockIdx.x * 32;
    const int z  = blockIdx.y;
    const bool gat = z < 4;
    const float* Wp = gat ? gatW + (size_t)z * 25600 : g1aW;
    const int t = threadIdx.x;
    const int col = t & 127, rg = t >> 7;
    float acc[16];
#pragma unroll
    for (int r = 0; r < 16; ++r) acc[r] = 0.f;

    for (int k0 = 0; k0 < 200; k0 += 32) {
        for (int idx = t; idx < 32 * 32; idx += 256) {
            int r = idx >> 5, kk = idx & 31;
            int k = k0 + kk;
            ldsA[r][kk] = (k < 200) ? xn[(size_t)(rt + r) * 200 + k] : 0.f;
        }
        for (int idx = t; idx < 32 * 128; idx += 256) {
            int kk = idx >> 7, c = idx & 127;
            int k = k0 + kk;
            ldsW[kk][c] = (k < 200) ? Wp[(size_t)k * 128 + c] : 0.f;
        }
        __syncthreads();
#pragma unroll 8
        for (int kk = 0; kk < 32; ++kk) {
            float wv = ldsW[kk][col];
#pragma unroll
            for (int r = 0; r < 16; ++r) acc[r] += ldsA[rg * 16 + r][kk] * wv;
        }
        __syncthreads();
    }
    if (gat) {
#pragma unroll
        for (int r = 0; r < 16; ++r) {
            ldsWh[rg * 16 + r][col] = acc[r];
            WhB[(size_t)(rt + rg * 16 + r) * 512 + z * 128 + col] = acc[r];
        }
        __syncthreads();
        int row = t >> 3, p = t & 7;
        const float* a = gata + z * 256;
        float s1 = 0.f, s2 = 0.f;
#pragma unroll
        for (int j = 0; j < 16; ++j) {
            int c = p * 16 + j;
            float v = ldsWh[row][c];
            s1 += v * a[c]; s2 += v * a[128 + c];
        }
        s1 += __shfl_xor(s1, 1); s1 += __shfl_xor(s1, 2); s1 += __shfl_xor(s1, 4);
        s2 += __shfl_xor(s2, 1); s2 += __shfl_xor(s2, 2); s2 += __shfl_xor(s2, 4);
        if (p == 0) { f1[z * N + rt + row] = s1; f2[z * N + rt + row] = s2; }
    } else {
        const float sc = BNF * BNF;
#pragma unroll
        for (int r = 0; r < 16; ++r)
            hbuf[(size_t)(rt + rg * 16 + r) * 128 + col] = sc * acc[r];
    }
}

// per-head attention: e-weights staged in LDS, single WhB gather pass
__global__ void k_att_head(const float* __restrict__ WhB, const float* __restrict__ f1,
                           const float* __restrict__ f2, const int* __restrict__ deg,
                           const int* __restrict__ idxs, float* __restrict__ hcat) {
    __shared__ float eW[MAXDEG];
    int n = blockIdx.x, h = blockIdx.y;
    int k = threadIdx.x;          // 128
    int d = deg[n];
    const int* row = idxs + (size_t)n * MAXDEG;
    float f1v = f1[h * N + n];
    const float* f2h = f2 + h * N;
    if (k < d) {
        float e = f1v + f2h[row[k]];
        eW[k] = e >= 0.f ? e : 0.2f * e;
    }
    __syncthreads();
    float mx = -1e30f;
    for (int j = 0; j < d; ++j) mx = fmaxf(mx, eW[j]);
    __syncthreads();
    if (k < d) eW[k] = __expf(eW[k] - mx);
    __syncthreads();
    float ssum = 0.f, acc = 0.f;
    for (int j = 0; j < d; ++j) ssum += eW[j];
    for (int j = 0; j < d; ++j)
        acc += eW[j] * WhB[(size_t)row[j] * 512 + h * 128 + k];
    float v = acc / ssum;
    v = v > 0.f ? v : __expf(v) - 1.f;
    hcat[(size_t)n * 512 + h * 128 + k] = v;
}

// WhO = hcat @ outW (32x64, K=512) + f1o/f2o row-dot epilogue
__global__ __launch_bounds__(256) void k_mmO(const float* __restrict__ hcat,
                                             const float* __restrict__ outW,
                                             const float* __restrict__ outa,
                                             float* __restrict__ WhO,
                                             float* __restrict__ f1o,
                                             float* __restrict__ f2o) {
    __shared__ float ldsA[32][33];
    __shared__ float ldsW[32][64];
    const int rt = blockIdx.x * 32;
    const int t = threadIdx.x;
    const int lane = t & 63, wg = t >> 6;
    float acc[8];
#pragma unroll
    for (int r = 0; r < 8; ++r) acc[r] = 0.f;

    for (int k0 = 0; k0 < 512; k0 += 32) {
        for (int idx = t; idx < 32 * 32; idx += 256) {
            int r = idx >> 5, kk = idx & 31;
            ldsA[r][kk] = hcat[(size_t)(rt + r) * 512 + k0 + kk];
        }
        for (int idx = t; idx < 32 * 64; idx += 256) {
            int kk = idx >> 6, c = idx & 63;
            ldsW[kk][c] = outW[(size_t)(k0 + kk) * 64 + c];
        }
        __syncthreads();
#pragma unroll 8
        for (int kk = 0; kk < 32; ++kk) {
            float wv = ldsW[kk][lane];
#pragma unroll
            for (int r = 0; r < 8; ++r) acc[r] += ldsA[wg * 8 + r][kk] * wv;
        }
        __syncthreads();
    }
#pragma unroll
    for (int r = 0; r < 8; ++r)
        WhO[(size_t)(rt + wg * 8 + r) * 64 + lane] = acc[r];
#pragma unroll
    for (int r = 0; r < 8; ++r) {
        float v1 = acc[r] * outa[lane];
        float v2 = acc[r] * outa[64 + lane];
#pragma unroll
        for (int off = 32; off; off >>= 1) {
            v1 += __shfl_down(v1, off);
            v2 += __shfl_down(v2, off);
        }
        if (lane == 0) { f1o[rt + wg * 8 + r] = v1; f2o[rt + wg * 8 + r] = v2; }
    }
}

// output attention (LDS-weights single gather) + elu + bn + lrelu + fusion
// + conv + bn + lrelu -> yT [64][2048] bf16
__global__ void k_att_out(const float* __restrict__ WhO, const float* __restrict__ f1o,
                          const float* __restrict__ f2o, const int* __restrict__ deg,
                          const int* __restrict__ idxs, const float* __restrict__ GCNx,
                          const float* __restrict__ Wf, const float* __restrict__ bfp,
                          const float* __restrict__ cw, const float* __restrict__ cb,
                          u16* __restrict__ yT) {
    __shared__ float eW[MAXDEG];
    int n = blockIdx.x;
    int k = threadIdx.x;   // 64
    int d = deg[n];
    const int* row = idxs + (size_t)n * MAXDEG;
    float f1v = f1o[n];
    for (int j = k; j < d; j += 64) {
        float e = f1v + f2o[row[j]];
        eW[j] = e >= 0.f ? e : 0.2f * e;
    }
    __syncthreads();
    float mx = -1e30f;
    for (int j = 0; j < d; ++j) mx = fmaxf(mx, eW[j]);
    __syncthreads();
    for (int j = k; j < d; j += 64) eW[j] = __expf(eW[j] - mx);
    __syncthreads();
    float ssum = 0.f, acc = 0.f;
    for (int j = 0; j < d; ++j) ssum += eW[j];
    for (int j = 0; j < d; ++j)
        acc += eW[j] * WhO[(size_t)row[j] * 64 + k];
    float v = acc / ssum;
    v = v > 0.f ? v : __expf(v) - 1.f;   // elu
    v *= BNF;
    float gat = v >= 0.f ? v : 0.01f * v;
    float g = GCNx[(size_t)n * 64 + k];
    float mn = fminf(g, gat), mxv = fmaxf(g, gat);
    float avg = g * Wf[k] + bfp[k] + gat * Wf[64 + k] + bfp[64 + k];
    float base = g + gat;
    float yv = cw[0] * (mn + base) + cw[1] * (mxv + base) + cw[2] * (avg + base) + cb[0];
    yv *= BNF;
    yv = yv >= 0.f ? yv : 0.2f * yv;
    yT[k * 2048 + n] = f2bf(yv);
}

// ---------------------------------------------------------------------------
// out[i,f] = sum_n Qbf[i,n]*yT[f,n]. Tile 128i x 64f, K-step 64, TRIPLE-buf
// LDS (dist-2 prefetch), counted vmcnt(12/6/0), grid 512, direct stores.
// ---------------------------------------------------------------------------
__global__ __launch_bounds__(256, 2) void k_final(const u16* __restrict__ Qbf,
                                                  const u16* __restrict__ yT,
                                                  float* __restrict__ out) {
    __shared__ __align__(16) u16 Aq[3][128 * 64];   // 16 KB per buf
    __shared__ __align__(16) u16 By[3][64 * 64];    // 8 KB per buf
    const int i0 = blockIdx.x * 128;
    const int t = threadIdx.x, w = t >> 6, l = t & 63;
    const int lrow = l >> 3;
    const int scol = (((l & 7) ^ ((l >> 3) & 7)) << 3);
    f32x4 acc[2][4];
#pragma unroll
    for (int a = 0; a < 2; ++a)
#pragma unroll
        for (int b = 0; b < 4; ++b) acc[a][b] = (f32x4){0.f, 0.f, 0.f, 0.f};

#define STAGE_F(buf, step)                                                          \
    {                                                                               \
        const size_t kc = (size_t)(step) * 64 + scol;                               \
        for (int s = w; s < 16; s += 4)                                             \
            gload16(&Qbf[(size_t)(i0 + s * 8 + lrow) * 2048 + kc],                  \
                    &Aq[buf][s * 512]);                                             \
        for (int s = w; s < 8; s += 4)                                              \
            gload16(&yT[(size_t)(s * 8 + lrow) * 2048 + kc],                        \
                    &By[buf][s * 512]);                                             \
    }

    STAGE_F(0, 0);
    STAGE_F(1, 1);
    for (int step = 0; step < 32; ++step) {
        const int cur = step % 3;
        if (step + 2 < 32) STAGE_F((step + 2) % 3, step + 2);
        // buf[cur] issued 2 steps back; 6 ops/wave/step after it per in-flight step
        if (step + 2 < 32)      asm volatile("s_waitcnt vmcnt(12)" ::: "memory");
        else if (step + 1 < 32) asm volatile("s_waitcnt vmcnt(6)"  ::: "memory");
        else                    asm volatile("s_waitcnt vmcnt(0)"  ::: "memory");
        __builtin_amdgcn_s_barrier();

        const u16* Ab = Aq[cur];
        const u16* Bb = By[cur];
#pragma unroll
        for (int sub = 0; sub < 2; ++sub) {
            const int c8 = sub * 4 + (l >> 4);
            Frag a[2];
#pragma unroll
            for (int it = 0; it < 2; ++it) {
                const int r = w * 32 + it * 16 + (l & 15);
                a[it].v = *(const short8*)&Ab[r * 64 + ((c8 ^ (r & 7)) << 3)];
            }
#pragma unroll
            for (int ft = 0; ft < 4; ++ft) {
                const int rb = ft * 16 + (l & 15);
                Frag b;
                b.v = *(const short8*)&Bb[rb * 64 + ((c8 ^ (rb & 7)) << 3)];
#pragma unroll
                for (int it = 0; it < 2; ++it)
                    acc[it][ft] = __builtin_amdgcn_mfma_f32_16x16x32_bf16(
                        a[it].v, b.v, acc[it][ft], 0, 0, 0);
            }
        }
        asm volatile("s_waitcnt lgkmcnt(0)" ::: "memory");
        __builtin_amdgcn_s_barrier();
    }
#undef STAGE_F
#pragma unroll
    for (int it = 0; it < 2; ++it)
#pragma unroll
        for (int ft = 0; ft < 4; ++ft) {
            const int i = i0 + w * 32 + it * 16 + ((l >> 4) << 2);
            const int f = ft * 16 + (l & 15);
#pragma unroll
            for (int r = 0; r < 4; ++r)
                out[(size_t)(i + r) * 64 + f] = acc[it][ft][r];
        }
}

extern "C" void kernel_launch(void* const* d_in, const int* in_sizes, int n_in,
                              void* d_out, int out_size, void* d_ws, size_t ws_size,
                              hipStream_t stream) {
    const float* x     = (const float*)d_in[0];
    const float* adj   = (const float*)d_in[1];
    const float* Q     = (const float*)d_in[2];
    const float* g1aW  = (const float*)d_in[3];
    const float* g1ab  = (const float*)d_in[4];
    const float* g1bW  = (const float*)d_in[5];
    const float* g1bb  = (const float*)d_in[6];
    const float* g2aW  = (const float*)d_in[7];
    const float* g2ab  = (const float*)d_in[8];
    const float* g2bW  = (const float*)d_in[9];
    const float* g2bb  = (const float*)d_in[10];
    const float* gatW  = (const float*)d_in[11];
    const float* gata  = (const float*)d_in[12];
    const float* outW  = (const float*)d_in[13];
    const float* outa  = (const float*)d_in[14];
    const float* Wf    = (const float*)d_in[15];
    const float* bfp   = (const float*)d_in[16];
    const float* convw = (const float*)d_in[17];
    const float* convb = (const float*)d_in[18];

    float* ws   = (float*)d_ws;
    float* xn   = ws + 411648;
    float* xg   = ws + 821248;
    float* xg2  = ws + 1230848;
    float* hbuf = ws + 1640448;
    float* zbuf = ws + 2050048;
    float* WhO  = ws + 2312192;
    float* GCNx = ws + 2443264;
    float* f1   = ws + 2836480;
    float* f2   = ws + 2844672;
    float* f1o  = ws + 2852864;
    float* f2o  = ws + 2854912;
    int*   deg  = (int*)(ws + 2856960);
    int*   idxs = (int*)(ws + 2859008);
    u16*   yT   = (u16*)(ws + 1640448);           // reuses hbuf region
    float* csPart = ws + 3000000;                 // 32*2048 f32
    float* S_part = ws + 4200000;                 // 32*409600 f32 = 52 MB
    u16*   Qbf    = (u16*)(ws + 71308864);        // 65536*2048 u16 = 256MB
    u16*   xfT    = (u16*)(ws + 138417728);       // 208*65536 u16

    float* out  = (float*)d_out;
    float* WhB  = out;             // 2048*512 scratch inside d_out
    float* hcat = out + 1048576;   // 2048*512 scratch inside d_out

    // ---- conversion + big S GEMM (fused: Q read once in f32) ----
    k_convX<<<512, 256, 0, stream>>>(x, xfT);
    k_bigS<<<1024, 256, 0, stream>>>(Q, xfT, Qbf, S_part, csPart);
    k_aux<<<2112, 256, 0, stream>>>(S_part, csPart, xn, xg, adj, deg, idxs);

    // ---- merged first GEMMs: GAT Wh (4 heads) + GCN mm1 ----
    k_wh5<<<dim3(64, 5), 256, 0, stream>>>(xn, gatW, gata, g1aW, WhB, f1, f2, hbuf);

    // ---- GCN + GAT chains ----
    k_spmm<<<N, 128, 0, stream>>>(hbuf, deg, idxs, g1ab, nullptr, zbuf, 128, 1.f, 1);
    k_att_head<<<dim3(N, 4), 128, 0, stream>>>(WhB, f1, f2, deg, idxs, hcat);
    k_mm<<<dim3(64, 4, 1), 256, 0, stream>>>(zbuf, g1bW, hbuf, 128, 200, 200, 0, 0, BNF);
    k_mmO<<<64, 256, 0, stream>>>(hcat, outW, outa, WhO, f1o, f2o);
    k_spmm<<<N, 128, 0, stream>>>(hbuf, deg, idxs, g1bb, xg, xg2, 200, BNF, 1);
    k_mm<<<dim3(64, 2, 1), 256, 0, stream>>>(xg2, g2aW, hbuf, 200, 128, 128, 0, 0, BNF);
    k_spmm<<<N, 128, 0, stream>>>(hbuf, deg, idxs, g2ab, nullptr, zbuf, 128, 1.f, 1);
    k_mm<<<dim3(64, 1, 1), 256, 0, stream>>>(zbuf, g2bW, hbuf, 128, 64, 64, 0, 0, BNF);
    k_spmm<<<N, 64, 0, stream>>>(hbuf, deg, idxs, g2bb, nullptr, GCNx, 64, BNF, 1);

    // ---- output attention + fusion -> yT ----
    k_att_out<<<N, 64, 0, stream>>>(WhO, f1o, f2o, deg, idxs, GCNx,
                                    Wf, bfp, convw, convb, yT);

    // ---- final projection (overwrites WhB/hcat scratch in d_out) ----
    k_final<<<512, 256, 0, stream>>>(Qbf, yT, out);
}